// Round 2
// baseline (1051.049 us; speedup 1.0000x reference)
//
#include <hip/hip_runtime.h>
#include <math.h>

// Shapes (hardcoded from reference): B=8,T=12,N=1000,D=256,H=8,R=32,HD=32,E=1024
#define MT 96000   // B*T*N tokens
#define DD 256
#define EE 1024
#define NBT 96     // B*T
#define NSEQ 1000

typedef __attribute__((ext_vector_type(8))) short bf16x8;
typedef __attribute__((ext_vector_type(4))) short bf16x4;
typedef __attribute__((ext_vector_type(4))) float f32x4;

__device__ __forceinline__ short f2b(float f) {
  union { float f; unsigned u; } v; v.f = f;
  unsigned r = (v.u + 0x7FFFu + ((v.u >> 16) & 1u)) >> 16;
  return (short)r;
}
__device__ __forceinline__ float b2f(short s) {
  union { unsigned u; float f; } v; v.u = ((unsigned)(unsigned short)s) << 16;
  return v.f;
}
__device__ __forceinline__ float sigf(float x) { return 1.f / (1.f + __expf(-x)); }
__device__ __forceinline__ f32x4 mfma16(bf16x8 a, bf16x8 b, f32x4 c) {
  return __builtin_amdgcn_mfma_f32_16x16x32_bf16(a, b, c, 0, 0, 0);
}
// packed f32x2 -> bf16x2 (RNE), single VALU inst
__device__ __forceinline__ unsigned cvtpk(float lo, float hi) {
  unsigned r;
  asm("v_cvt_pk_bf16_f32 %0, %1, %2" : "=v"(r) : "v"(lo), "v"(hi));
  return r;
}

// ---------------------------------------------------------------------------
// K0: weight prep. Transposed bf16 weights ([out][in] so B-fragments are 16B
// contiguous k-octets), plus fused Wqk = (Wq . key)/sqrt(HD) and bqk.
// ---------------------------------------------------------------------------
__global__ __launch_bounds__(256) void k_prep(
    const float* __restrict__ Wq, const float* __restrict__ bq,
    const float* __restrict__ key, const float* __restrict__ Wv,
    const float* __restrict__ W1, const float* __restrict__ W2,
    const float* __restrict__ W3,
    short* __restrict__ W1t, short* __restrict__ W2t, short* __restrict__ W3t,
    short* __restrict__ Wvt, short* __restrict__ Wqkt, float* __restrict__ bqk)
{
  int i = blockIdx.x * 256 + threadIdx.x;   // 0 .. 262143
  { int e = i >> 8, c = i & 255;            // W1t/W2t: [e][c]
    W1t[i] = f2b(W1[c * EE + e]);
    W2t[i] = f2b(W2[c * EE + e]); }
  { int n = i >> 10, e = i & 1023;          // W3t: [n][e]
    W3t[i] = f2b(W3[e * DD + n]); }
  if (i < 65536) {
    int n = i >> 8, c = i & 255;
    Wvt[i] = f2b(Wv[c * DD + n]);           // Wvt: [n][c]
    int h = n >> 5, r = n & 31;
    float acc = 0.f;
    for (int d = 0; d < 32; ++d)
      acc += Wq[c * DD + h * 32 + d] * key[(r * 8 + h) * 32 + d];
    Wqkt[i] = f2b(acc * 0.17677669529663687f);  // 1/sqrt(32)
  }
  if (i < 256) {
    int h = i >> 5, r = i & 31;
    float acc = 0.f;
    for (int d = 0; d < 32; ++d)
      acc += bq[h * 32 + d] * key[(r * 8 + h) * 32 + d];
    bqk[i] = acc * 0.17677669529663687f;
  }
}

// ---------------------------------------------------------------------------
// K1: fused RMSNorm: x1 = rms(x)*w1 ; z1 = rms(sg*x1 + sd*z)*w2. bf16 out.
// One wave per token (256 elems = float4/lane).
// ---------------------------------------------------------------------------
__global__ __launch_bounds__(256) void k_norm(
    const float* __restrict__ x, const float* __restrict__ z,
    const float* __restrict__ nw1, const float* __restrict__ nw2,
    const float* __restrict__ gamma, const float* __restrict__ delta,
    short* __restrict__ x1bp, short* __restrict__ z1bp)
{
  int tok = blockIdx.x * 4 + (threadIdx.x >> 6);
  int lane = threadIdx.x & 63;
  size_t rbase = (size_t)tok * DD;
  float4 xv = ((const float4*)(x + rbase))[lane];
  float ss = xv.x*xv.x + xv.y*xv.y + xv.z*xv.z + xv.w*xv.w;
  #pragma unroll
  for (int mm = 1; mm < 64; mm <<= 1) ss += __shfl_xor(ss, mm);
  float inv = rsqrtf(ss * 0.00390625f + 1e-6f);
  float4 wv = ((const float4*)nw1)[lane];
  float xa = xv.x * inv * wv.x, xb = xv.y * inv * wv.y,
        xc = xv.z * inv * wv.z, xd = xv.w * inv * wv.w;
  bf16x4 xo = { f2b(xa), f2b(xb), f2b(xc), f2b(xd) };
  ((bf16x4*)(x1bp + rbase))[lane] = xo;
  float sg = sigf(gamma[0]), sd = sigf(delta[0]);
  float4 zv = ((const float4*)(z + rbase))[lane];
  float t0 = sg*xa + sd*zv.x, t1 = sg*xb + sd*zv.y,
        t2 = sg*xc + sd*zv.z, t3 = sg*xd + sd*zv.w;
  float s2 = t0*t0 + t1*t1 + t2*t2 + t3*t3;
  #pragma unroll
  for (int mm = 1; mm < 64; mm <<= 1) s2 += __shfl_xor(s2, mm);
  float inv2 = rsqrtf(s2 * 0.00390625f + 1e-6f);
  float4 w2v = ((const float4*)nw2)[lane];
  bf16x4 zo = { f2b(t0*inv2*w2v.x), f2b(t1*inv2*w2v.y),
                f2b(t2*inv2*w2v.z), f2b(t3*inv2*w2v.w) };
  ((bf16x4*)(z1bp + rbase))[lane] = zo;
}

// ---------------------------------------------------------------------------
// K2/K3: C_bf16[MT,256] = A_bf16[MT,256] @ Bt^T + bias. Bt is [256][256] in
// [n][k] layout. 64x64 tile, 4 waves each 32x32 (2x2 MFMA tiles).
// ---------------------------------------------------------------------------
__global__ __launch_bounds__(256) void k_gemm256(
    const short* __restrict__ A, const short* __restrict__ Bt,
    const float* __restrict__ bias, short* __restrict__ C)
{
  __shared__ __align__(16) short As[64 * 40];  // +8 pad: 2-way-at-worst banks
  __shared__ __align__(16) short Bs[64 * 40];
  int row0 = blockIdx.x * 64, col0 = blockIdx.y * 64;
  int tid = threadIdx.x, lane = tid & 63, w = tid >> 6;
  int mh = (w & 1) * 32, nh = (w >> 1) * 32;
  int l15 = lane & 15, ko = (lane >> 4) * 8;
  int lrow = tid >> 2, lch = (tid & 3) * 8;
  f32x4 acc[2][2] = {};
  for (int k0 = 0; k0 < 256; k0 += 32) {
    *(bf16x8*)&As[lrow * 40 + lch] = *(const bf16x8*)&A[(row0 + lrow) * 256 + k0 + lch];
    *(bf16x8*)&Bs[lrow * 40 + lch] = *(const bf16x8*)&Bt[(col0 + lrow) * 256 + k0 + lch];
    __syncthreads();
    bf16x8 af[2], bfr[2];
    #pragma unroll
    for (int t = 0; t < 2; ++t) {
      af[t]  = *(const bf16x8*)&As[(mh + t * 16 + l15) * 40 + ko];
      bfr[t] = *(const bf16x8*)&Bs[(nh + t * 16 + l15) * 40 + ko];
    }
    #pragma unroll
    for (int tm = 0; tm < 2; ++tm)
      #pragma unroll
      for (int tn = 0; tn < 2; ++tn)
        acc[tm][tn] = mfma16(af[tm], bfr[tn], acc[tm][tn]);
    __syncthreads();
  }
  #pragma unroll
  for (int tm = 0; tm < 2; ++tm)
    #pragma unroll
    for (int tn = 0; tn < 2; ++tn) {
      int n = col0 + nh + tn * 16 + l15;
      float bv = bias[n];
      #pragma unroll
      for (int r = 0; r < 4; ++r) {
        int m = row0 + mh + tm * 16 + (lane >> 4) * 4 + r;
        C[m * 256 + n] = f2b(acc[tm][tn][r] + bv);
      }
    }
}

// ---------------------------------------------------------------------------
// K4: fused SwiGLU FFN v3 — weight-streaming LDS pipeline.
// 64 rows/block. A-tile held in REGISTERS (af[2][8], loaded once via LDS).
// Weights stream through a double-buffered LDS slice (issue-early/write-late):
//   S1 slice: W1||W2 [64e x 32k], row-pad 40 (bank-spread verified)
//   S2 slice: W3 [256n x 32e], granule XOR-swizzle g^((n>>2)&3)
// Per phase: barrier -> issue next-slice global loads -> MFMA current slice
// -> ds_write next slice. One barrier per phase; load latency hides under
// compute + the second resident block.
// Stage1 uses swapped operands (H^T out, verified in prior round): b64 Hs
// writes, biases folded into MFMA C-init, cvtpk bf16 pack, nt streaming.
// ---------------------------------------------------------------------------
__global__ __launch_bounds__(256, 2) void k_ffn(
    const short* __restrict__ x1bp,
    const short* __restrict__ W1t, const short* __restrict__ W2t,
    const short* __restrict__ W3t,
    const float* __restrict__ b1, const float* __restrict__ b2,
    const float* __restrict__ b3, const float* __restrict__ alpha,
    float* __restrict__ out)
{
  __shared__ __align__(16) short WS[16896];    // 33792B: As staging, then Wbuf[2][8448]
  __shared__ __align__(16) short Hs[64 * 72];  // 9216B
  int row0 = blockIdx.x * 64;
  int tid = threadIdx.x, lane = tid & 63, w = tid >> 6;
  int l15 = lane & 15, g = lane >> 4;          // g: k/e octet selector 0..3
  int mh = w & 1, q2 = w >> 1;                 // q2: e-half (S1) / n-half (S2)
  int se = tid >> 2, skv = tid & 3;            // S1 staging coords
  int xsw = (l15 >> 2) & 3;                    // S2 read swizzle

  // ---- stage A (64x256) into WS[64][264], nt loads ----
  #pragma unroll
  for (int it = 0; it < 8; ++it) {
    int idx = it * 256 + tid;
    int rw = idx >> 5, ch = (idx & 31) * 8;
    const bf16x8* src = (const bf16x8*)&x1bp[(size_t)(row0 + rw) * 256 + ch];
    *(bf16x8*)&WS[rw * 264 + ch] = __builtin_nontemporal_load(src);
  }
  __syncthreads();
  // ---- af regs: wave's m-half, full K ----
  bf16x8 af[2][8];
  #pragma unroll
  for (int kk = 0; kk < 8; ++kk)
    #pragma unroll
    for (int tm = 0; tm < 2; ++tm)
      af[tm][kk] = *(const bf16x8*)&WS[(mh * 32 + tm * 16 + l15) * 264 + kk * 32 + g * 8];
  __syncthreads();
  // ---- oacc init with b3 ----
  f32x4 oacc[2][8];
  #pragma unroll
  for (int tn = 0; tn < 8; ++tn) {
    float bb = b3[q2 * 128 + tn * 16 + l15];
    #pragma unroll
    for (int tm = 0; tm < 2; ++tm) oacc[tm][tn] = (f32x4){bb, bb, bb, bb};
  }
  // ---- prologue: stage slice (ec=0, S1 kk=0) into buf0 ----
  {
    bf16x8 r1 = *(const bf16x8*)&W1t[(size_t)se * 256 + skv * 8];
    bf16x8 r2 = *(const bf16x8*)&W2t[(size_t)se * 256 + skv * 8];
    *(bf16x8*)&WS[se * 40 + skv * 8] = r1;
    *(bf16x8*)&WS[2560 + se * 40 + skv * 8] = r2;
  }
  for (int ec = 0; ec < 16; ++ec) {
    int e0 = ec * 64;
    // h accumulators init with b1/b2 (rows e = base + 4g + r)
    f32x4 h1[2][2], h2[2][2];
    #pragma unroll
    for (int et = 0; et < 2; ++et) {
      float4 c1 = *(const float4*)&b1[e0 + q2 * 32 + et * 16 + g * 4];
      float4 c2 = *(const float4*)&b2[e0 + q2 * 32 + et * 16 + g * 4];
      #pragma unroll
      for (int tm = 0; tm < 2; ++tm) {
        h1[tm][et] = (f32x4){c1.x, c1.y, c1.z, c1.w};
        h2[tm][et] = (f32x4){c2.x, c2.y, c2.z, c2.w};
      }
    }
    // ---- stage1: 8 phases over K ----
    #pragma unroll
    for (int kk = 0; kk < 8; ++kk) {
      __syncthreads();
      int bo = (kk & 1) * 8448, bn = ((kk + 1) & 1) * 8448;
      bf16x8 r1, r2, s0, s1, s2, s3;
      if (kk < 7) {  // next = S1 (ec, kk+1)
        r1 = *(const bf16x8*)&W1t[(size_t)(e0 + se) * 256 + (kk + 1) * 32 + skv * 8];
        r2 = *(const bf16x8*)&W2t[(size_t)(e0 + se) * 256 + (kk + 1) * 32 + skv * 8];
      } else {       // next = S2 (ec, k2=0): n = tid, 4 contiguous vec8
        s0 = *(const bf16x8*)&W3t[(size_t)tid * 1024 + e0 + 0];
        s1 = *(const bf16x8*)&W3t[(size_t)tid * 1024 + e0 + 8];
        s2 = *(const bf16x8*)&W3t[(size_t)tid * 1024 + e0 + 16];
        s3 = *(const bf16x8*)&W3t[(size_t)tid * 1024 + e0 + 24];
      }
      // consume S1 slice kk
      bf16x8 w1f[2], w2f[2];
      #pragma unroll
      for (int et = 0; et < 2; ++et) {
        w1f[et] = *(const bf16x8*)&WS[bo + (q2 * 32 + et * 16 + l15) * 40 + g * 8];
        w2f[et] = *(const bf16x8*)&WS[bo + 2560 + (q2 * 32 + et * 16 + l15) * 40 + g * 8];
      }
      #pragma unroll
      for (int et = 0; et < 2; ++et)
        #pragma unroll
        for (int tm = 0; tm < 2; ++tm) {
          h1[tm][et] = mfma16(w1f[et], af[tm][kk], h1[tm][et]);
          h2[tm][et] = mfma16(w2f[et], af[tm][kk], h2[tm][et]);
        }
      // write next slice
      if (kk < 7) {
        *(bf16x8*)&WS[bn + se * 40 + skv * 8] = r1;
        *(bf16x8*)&WS[bn + 2560 + se * 40 + skv * 8] = r2;
      } else {
        int nsw = (tid >> 2) & 3;
        *(bf16x8*)&WS[bn + tid * 32 + ((0 ^ nsw) * 8)] = s0;
        *(bf16x8*)&WS[bn + tid * 32 + ((1 ^ nsw) * 8)] = s1;
        *(bf16x8*)&WS[bn + tid * 32 + ((2 ^ nsw) * 8)] = s2;
        *(bf16x8*)&WS[bn + tid * 32 + ((3 ^ nsw) * 8)] = s3;
      }
    }
    // ---- silu epilogue -> Hs (before next phase's barrier) ----
    #pragma unroll
    for (int tm = 0; tm < 2; ++tm)
      #pragma unroll
      for (int et = 0; et < 2; ++et) {
        int m = mh * 32 + tm * 16 + l15;
        int eb = q2 * 32 + et * 16 + g * 4;
        float a0 = h1[tm][et][0], a1 = h1[tm][et][1],
              a2 = h1[tm][et][2], a3 = h1[tm][et][3];
        float v0 = a0 * h2[tm][et][0] * sigf(a0);
        float v1 = a1 * h2[tm][et][1] * sigf(a1);
        float v2 = a2 * h2[tm][et][2] * sigf(a2);
        float v3 = a3 * h2[tm][et][3] * sigf(a3);
        uint2 pk;
        pk.x = cvtpk(v0, v1);
        pk.y = cvtpk(v2, v3);
        *(uint2*)&Hs[m * 72 + eb] = pk;
      }
    // ---- stage2: 2 phases over the 64-e chunk ----
    #pragma unroll
    for (int k2 = 0; k2 < 2; ++k2) {
      __syncthreads();
      int bo = (k2 & 1) * 8448, bn = ((k2 + 1) & 1) * 8448;
      bf16x8 r1, r2, s0, s1, s2, s3;
      bool haveS1 = false;
      if (k2 == 0) {  // next = S2 (ec, k2=1)
        s0 = *(const bf16x8*)&W3t[(size_t)tid * 1024 + e0 + 32 + 0];
        s1 = *(const bf16x8*)&W3t[(size_t)tid * 1024 + e0 + 32 + 8];
        s2 = *(const bf16x8*)&W3t[(size_t)tid * 1024 + e0 + 32 + 16];
        s3 = *(const bf16x8*)&W3t[(size_t)tid * 1024 + e0 + 32 + 24];
      } else if (ec < 15) {  // next = S1 (ec+1, kk=0)
        haveS1 = true;
        r1 = *(const bf16x8*)&W1t[(size_t)(e0 + 64 + se) * 256 + skv * 8];
        r2 = *(const bf16x8*)&W2t[(size_t)(e0 + 64 + se) * 256 + skv * 8];
      }
      // consume S2 slice k2
      bf16x8 hf[2];
      #pragma unroll
      for (int tm = 0; tm < 2; ++tm)
        hf[tm] = *(const bf16x8*)&Hs[(mh * 32 + tm * 16 + l15) * 72 + k2 * 32 + g * 8];
      #pragma unroll
      for (int tn = 0; tn < 8; ++tn) {
        bf16x8 w3f = *(const bf16x8*)&WS[bo + (q2 * 128 + tn * 16 + l15) * 32 + ((g ^ xsw) * 8)];
        #pragma unroll
        for (int tm = 0; tm < 2; ++tm)
          oacc[tm][tn] = mfma16(hf[tm], w3f, oacc[tm][tn]);
      }
      // write next slice
      if (k2 == 0) {
        int nsw = (tid >> 2) & 3;
        *(bf16x8*)&WS[bn + tid * 32 + ((0 ^ nsw) * 8)] = s0;
        *(bf16x8*)&WS[bn + tid * 32 + ((1 ^ nsw) * 8)] = s1;
        *(bf16x8*)&WS[bn + tid * 32 + ((2 ^ nsw) * 8)] = s2;
        *(bf16x8*)&WS[bn + tid * 32 + ((3 ^ nsw) * 8)] = s3;
      } else if (haveS1) {
        *(bf16x8*)&WS[bn + se * 40 + skv * 8] = r1;
        *(bf16x8*)&WS[bn + 2560 + se * 40 + skv * 8] = r2;
      }
    }
  }
  // ---- final out write (nt) ----
  float sa = sigf(alpha[0]);
  #pragma unroll
  for (int tn = 0; tn < 8; ++tn) {
    int n = q2 * 128 + tn * 16 + l15;
    #pragma unroll
    for (int tm = 0; tm < 2; ++tm)
      #pragma unroll
      for (int r = 0; r < 4; ++r) {
        int m = row0 + mh * 32 + tm * 16 + g * 4 + r;
        __builtin_nontemporal_store(sa * oacc[tm][tn][r], &out[(size_t)m * 256 + n]);
      }
  }
}

// ---------------------------------------------------------------------------
// K5: attention pass 1, barrier-free main loop. One block per (b,t,h).
// All cross-lane traffic is intra-32-lane (__shfl width 32); col-stat and
// v1 partial merges across halves via __shfl_xor(...,32); one barrier total.
// ---------------------------------------------------------------------------
__global__ __launch_bounds__(256) void k_attn1(
    const short* __restrict__ attnb, const short* __restrict__ xvb,
    float* __restrict__ v1buf, float* __restrict__ colmax, float* __restrict__ colsum)
{
  __shared__ float red[4][32][33];
  __shared__ float mred[4][32], sred[4][32];
  int gid = blockIdx.x;            // bt*8 + h
  int bt = gid >> 3, h = gid & 7;
  int tid = threadIdx.x, lane = tid & 63, wv = tid >> 6;
  int r = lane & 31;
  int nl = (wv << 1) | (lane >> 5);   // 0..7
  int base = bt * NSEQ;
  float accd[32];
  #pragma unroll
  for (int d = 0; d < 32; ++d) accd[d] = 0.f;
  float mrun = -1e30f, srun = 0.f;
  const short* ap = attnb + (size_t)(base + nl) * 256 + h * 32 + r;
  const short* xp = xvb   + (size_t)(base + nl) * 256 + h * 32 + r;
  for (int it = 0; it < 125; ++it) {
    float a = b2f(ap[it * 8 * 256]);
    float rmax = a;
    #pragma unroll
    for (int mm = 16; mm > 0; mm >>= 1) rmax = fmaxf(rmax, __shfl_xor(rmax, mm));
    float ea = __expf(a - rmax);
    float rsum = ea;
    #pragma unroll
    for (int mm = 16; mm > 0; mm >>= 1) rsum += __shfl_xor(rsum, mm);
    float p1 = ea / rsum;
    float nm = fmaxf(mrun, a);                      // online col stats
    srun = srun * __expf(mrun - nm) + __expf(a - nm);
    mrun = nm;
    float xvv = b2f(xp[it * 8 * 256]);
    #pragma unroll
    for (int d = 0; d < 32; ++d) accd[d] += p1 * __shfl(xvv, d, 32);
  }
  // merge the two halves of each wave (nl pairs)
  #pragma unroll
  for (int d = 0; d < 32; ++d) accd[d] += __shfl_xor(accd[d], 32);
  float mo = __shfl_xor(mrun, 32), so = __shfl_xor(srun, 32);
  float M2 = fmaxf(mrun, mo);
  float S2 = srun * __expf(mrun - M2) + so * __expf(mo - M2);
  if (lane < 32) {
    #pragma unroll
    for (int d = 0; d < 32; ++d) red[wv][r][d] = accd[d];
    mred[wv][r] = M2; sred[wv][r] = S2;
  }
  __syncthreads();
  #pragma unroll
  for (int q = 0; q < 4; ++q) {
    int idx = q * 256 + tid, rr = idx >> 5, dd = idx & 31;
    v1buf[gid * 1024 + idx] =
        red[0][rr][dd] + red[1][rr][dd] + red[2][rr][dd] + red[3][rr][dd];
  }
  if (tid < 32) {
    float Mv = fmaxf(fmaxf(mred[0][tid], mred[1][tid]),
                     fmaxf(mred[2][tid], mred[3][tid]));
    float Sv = 0.f;
    #pragma unroll
    for (int j = 0; j < 4; ++j) Sv += sred[j][tid] * __expf(mred[j][tid] - Mv);
    colmax[gid * 32 + tid] = Mv;
    colsum[gid * 32 + tid] = Sv;
  }
}

// ---------------------------------------------------------------------------
// K6: attention pass 2 + final blend, barrier-free main loop.
// v2[n][d] = sum_r P2[n][r]*v1[r][d]; P2 shared intra-32-lane via __shfl.
// Per-thread col stats hoisted to registers (column fixed per thread).
// ---------------------------------------------------------------------------
__global__ __launch_bounds__(256) void k_attn2(
    const short* __restrict__ attnb, const short* __restrict__ xvb,
    const float* __restrict__ v1buf, const float* __restrict__ colmax,
    const float* __restrict__ colsum, const float* __restrict__ mha_alpha,
    const float* __restrict__ mha_beta, const float* __restrict__ beta,
    float* __restrict__ out)
{
  __shared__ float v1s[8 * 1024];
  int bt = blockIdx.x, chunk = blockIdx.y;
  int tid = threadIdx.x;
  #pragma unroll
  for (int q = 0; q < 8; ++q)
    ((float4*)v1s)[q * 256 + tid] = ((const float4*)(v1buf + bt * 8192))[q * 256 + tid];
  int h = tid >> 5, d = tid & 31;
  float cm  = colmax[bt * 256 + tid];
  float rcs = 1.f / colsum[bt * 256 + tid];
  float sa = sigf(mha_alpha[h]), sb = sigf(mha_beta[h]);
  float sbeta = sigf(beta[0]);
  __syncthreads();
  const float* v1p = v1s + h * 1024 + d;
  int tok0 = bt * NSEQ + chunk * 100;
  for (int tl = 0; tl < 100; ++tl) {
    int tok = tok0 + tl;
    float a = b2f(attnb[(size_t)tok * 256 + tid]);
    float p2 = __expf(a - cm) * rcs;
    float xvv = b2f(xvb[(size_t)tok * 256 + tid]);
    float v2 = 0.f;
    #pragma unroll
    for (int rr = 0; rr < 32; ++rr)
      v2 += __shfl(p2, rr, 32) * v1p[rr * 32];
    out[(size_t)tok * 256 + tid] += sbeta * (sa * xvv + sb * v2);
  }
}

// ---------------------------------------------------------------------------
extern "C" void kernel_launch(void* const* d_in, const int* in_sizes, int n_in,
                              void* d_out, int out_size, void* d_ws, size_t ws_size,
                              hipStream_t stream) {
  const float* x        = (const float*)d_in[0];
  const float* z        = (const float*)d_in[1];
  const float* norm1_w  = (const float*)d_in[2];
  const float* norm2_w  = (const float*)d_in[3];
  const float* alpha    = (const float*)d_in[4];
  const float* beta     = (const float*)d_in[5];
  const float* gamma    = (const float*)d_in[6];
  const float* delta    = (const float*)d_in[7];
  const float* Wq       = (const float*)d_in[8];
  const float* bq       = (const float*)d_in[9];
  const float* key      = (const float*)d_in[10];
  const float* Wv       = (const float*)d_in[11];
  const float* bv       = (const float*)d_in[12];
  const float* mha_a    = (const float*)d_in[13];
  const float* mha_b    = (const float*)d_in[14];
  const float* W1       = (const float*)d_in[15];
  const float* b1       = (const float*)d_in[16];
  const float* W2       = (const float*)d_in[17];
  const float* b2       = (const float*)d_in[18];
  const float* W3       = (const float*)d_in[19];
  const float* b3       = (const float*)d_in[20];
  float* out = (float*)d_out;
  char* ws = (char*)d_ws;

  short* x1b   = (short*)(ws);
  short* z1b   = (short*)(ws + 49152000);
  short* xvb   = (short*)(ws + 98304000);
  short* attnb = (short*)(ws + 147456000);
  short* W1t   = (short*)(ws + 196608000);
  short* W2t   = (short*)(ws + 197132288);
  short* W3t   = (short*)(ws + 197656576);
  short* Wvt   = (short*)(ws + 198180864);
  short* Wqkt  = (short*)(ws + 198311936);
  float* bqk   = (float*)(ws + 198443008);
  float* v1buf = (float*)(ws + 198444032);
  float* colmax= (float*)(ws + 201589760);
  float* colsum= (float*)(ws + 201688064);

  hipLaunchKernelGGL(k_prep, dim3(1024), dim3(256), 0, stream,
                     Wq, bq, key, Wv, W1, W2, W3, W1t, W2t, W3t, Wvt, Wqkt, bqk);
  hipLaunchKernelGGL(k_norm, dim3(MT / 4), dim3(256), 0, stream,
                     x, z, norm1_w, norm2_w, gamma, delta, x1b, z1b);
  hipLaunchKernelGGL(k_gemm256, dim3(MT / 64, 4), dim3(256), 0, stream,
                     z1b, Wqkt, bqk, attnb);
  hipLaunchKernelGGL(k_gemm256, dim3(MT / 64, 4), dim3(256), 0, stream,
                     x1b, Wvt, bv, xvb);
  hipLaunchKernelGGL(k_ffn, dim3(MT / 64), dim3(256), 0, stream,
                     x1b, W1t, W2t, W3t, b1, b2, b3, alpha, out);
  hipLaunchKernelGGL(k_attn1, dim3(NBT * 8), dim3(256), 0, stream,
                     attnb, xvb, v1buf, colmax, colsum);
  hipLaunchKernelGGL(k_attn2, dim3(NBT, 10), dim3(256), 0, stream,
                     attnb, xvb, v1buf, colmax, colsum, mha_a, mha_b, beta, out);
}

// Round 3
// 884.038 us; speedup vs baseline: 1.1889x; 1.1889x over previous
//
#include <hip/hip_runtime.h>
#include <math.h>

// Shapes (hardcoded from reference): B=8,T=12,N=1000,D=256,H=8,R=32,HD=32,E=1024
#define MT 96000   // B*T*N tokens
#define DD 256
#define EE 1024
#define NBT 96     // B*T
#define NSEQ 1000

typedef __attribute__((ext_vector_type(8))) short bf16x8;
typedef __attribute__((ext_vector_type(4))) short bf16x4;
typedef __attribute__((ext_vector_type(4))) float f32x4;

__device__ __forceinline__ short f2b(float f) {
  union { float f; unsigned u; } v; v.f = f;
  unsigned r = (v.u + 0x7FFFu + ((v.u >> 16) & 1u)) >> 16;
  return (short)r;
}
__device__ __forceinline__ float b2f(short s) {
  union { unsigned u; float f; } v; v.u = ((unsigned)(unsigned short)s) << 16;
  return v.f;
}
__device__ __forceinline__ float sigf(float x) { return 1.f / (1.f + __expf(-x)); }
__device__ __forceinline__ f32x4 mfma16(bf16x8 a, bf16x8 b, f32x4 c) {
  return __builtin_amdgcn_mfma_f32_16x16x32_bf16(a, b, c, 0, 0, 0);
}
// packed f32x2 -> bf16x2 (RNE), single VALU inst
__device__ __forceinline__ unsigned cvtpk(float lo, float hi) {
  unsigned r;
  asm("v_cvt_pk_bf16_f32 %0, %1, %2" : "=v"(r) : "v"(lo), "v"(hi));
  return r;
}

// ---------------------------------------------------------------------------
// K0: weight prep. Transposed bf16 weights ([out][in] so B-fragments are 16B
// contiguous k-octets), plus fused Wqk = (Wq . key)/sqrt(HD) and bqk.
// ---------------------------------------------------------------------------
__global__ __launch_bounds__(256) void k_prep(
    const float* __restrict__ Wq, const float* __restrict__ bq,
    const float* __restrict__ key, const float* __restrict__ Wv,
    const float* __restrict__ W1, const float* __restrict__ W2,
    const float* __restrict__ W3,
    short* __restrict__ W1t, short* __restrict__ W2t, short* __restrict__ W3t,
    short* __restrict__ Wvt, short* __restrict__ Wqkt, float* __restrict__ bqk)
{
  int i = blockIdx.x * 256 + threadIdx.x;   // 0 .. 262143
  { int e = i >> 8, c = i & 255;            // W1t/W2t: [e][c]
    W1t[i] = f2b(W1[c * EE + e]);
    W2t[i] = f2b(W2[c * EE + e]); }
  { int n = i >> 10, e = i & 1023;          // W3t: [n][e]
    W3t[i] = f2b(W3[e * DD + n]); }
  if (i < 65536) {
    int n = i >> 8, c = i & 255;
    Wvt[i] = f2b(Wv[c * DD + n]);           // Wvt: [n][c]
    int h = n >> 5, r = n & 31;
    float acc = 0.f;
    for (int d = 0; d < 32; ++d)
      acc += Wq[c * DD + h * 32 + d] * key[(r * 8 + h) * 32 + d];
    Wqkt[i] = f2b(acc * 0.17677669529663687f);  // 1/sqrt(32)
  }
  if (i < 256) {
    int h = i >> 5, r = i & 31;
    float acc = 0.f;
    for (int d = 0; d < 32; ++d)
      acc += bq[h * 32 + d] * key[(r * 8 + h) * 32 + d];
    bqk[i] = acc * 0.17677669529663687f;
  }
}

// ---------------------------------------------------------------------------
// K1: fused RMSNorm: x1 = rms(x)*w1 ; z1 = rms(sg*x1 + sd*z)*w2. bf16 out.
// One wave per token (256 elems = float4/lane).
// ---------------------------------------------------------------------------
__global__ __launch_bounds__(256) void k_norm(
    const float* __restrict__ x, const float* __restrict__ z,
    const float* __restrict__ nw1, const float* __restrict__ nw2,
    const float* __restrict__ gamma, const float* __restrict__ delta,
    short* __restrict__ x1bp, short* __restrict__ z1bp)
{
  int tok = blockIdx.x * 4 + (threadIdx.x >> 6);
  int lane = threadIdx.x & 63;
  size_t rbase = (size_t)tok * DD;
  float4 xv = ((const float4*)(x + rbase))[lane];
  float ss = xv.x*xv.x + xv.y*xv.y + xv.z*xv.z + xv.w*xv.w;
  #pragma unroll
  for (int mm = 1; mm < 64; mm <<= 1) ss += __shfl_xor(ss, mm);
  float inv = rsqrtf(ss * 0.00390625f + 1e-6f);
  float4 wv = ((const float4*)nw1)[lane];
  float xa = xv.x * inv * wv.x, xb = xv.y * inv * wv.y,
        xc = xv.z * inv * wv.z, xd = xv.w * inv * wv.w;
  bf16x4 xo = { f2b(xa), f2b(xb), f2b(xc), f2b(xd) };
  ((bf16x4*)(x1bp + rbase))[lane] = xo;
  float sg = sigf(gamma[0]), sd = sigf(delta[0]);
  float4 zv = ((const float4*)(z + rbase))[lane];
  float t0 = sg*xa + sd*zv.x, t1 = sg*xb + sd*zv.y,
        t2 = sg*xc + sd*zv.z, t3 = sg*xd + sd*zv.w;
  float s2 = t0*t0 + t1*t1 + t2*t2 + t3*t3;
  #pragma unroll
  for (int mm = 1; mm < 64; mm <<= 1) s2 += __shfl_xor(s2, mm);
  float inv2 = rsqrtf(s2 * 0.00390625f + 1e-6f);
  float4 w2v = ((const float4*)nw2)[lane];
  bf16x4 zo = { f2b(t0*inv2*w2v.x), f2b(t1*inv2*w2v.y),
                f2b(t2*inv2*w2v.z), f2b(t3*inv2*w2v.w) };
  ((bf16x4*)(z1bp + rbase))[lane] = zo;
}

// ---------------------------------------------------------------------------
// K2/K3: C_bf16[MT,256] = A_bf16[MT,256] @ Bt^T + bias. Bt is [256][256] in
// [n][k] layout. 64x64 tile, 4 waves each 32x32 (2x2 MFMA tiles).
// ---------------------------------------------------------------------------
__global__ __launch_bounds__(256) void k_gemm256(
    const short* __restrict__ A, const short* __restrict__ Bt,
    const float* __restrict__ bias, short* __restrict__ C)
{
  __shared__ __align__(16) short As[64 * 40];  // +8 pad: 2-way-at-worst banks
  __shared__ __align__(16) short Bs[64 * 40];
  int row0 = blockIdx.x * 64, col0 = blockIdx.y * 64;
  int tid = threadIdx.x, lane = tid & 63, w = tid >> 6;
  int mh = (w & 1) * 32, nh = (w >> 1) * 32;
  int l15 = lane & 15, ko = (lane >> 4) * 8;
  int lrow = tid >> 2, lch = (tid & 3) * 8;
  f32x4 acc[2][2] = {};
  for (int k0 = 0; k0 < 256; k0 += 32) {
    *(bf16x8*)&As[lrow * 40 + lch] = *(const bf16x8*)&A[(row0 + lrow) * 256 + k0 + lch];
    *(bf16x8*)&Bs[lrow * 40 + lch] = *(const bf16x8*)&Bt[(col0 + lrow) * 256 + k0 + lch];
    __syncthreads();
    bf16x8 af[2], bfr[2];
    #pragma unroll
    for (int t = 0; t < 2; ++t) {
      af[t]  = *(const bf16x8*)&As[(mh + t * 16 + l15) * 40 + ko];
      bfr[t] = *(const bf16x8*)&Bs[(nh + t * 16 + l15) * 40 + ko];
    }
    #pragma unroll
    for (int tm = 0; tm < 2; ++tm)
      #pragma unroll
      for (int tn = 0; tn < 2; ++tn)
        acc[tm][tn] = mfma16(af[tm], bfr[tn], acc[tm][tn]);
    __syncthreads();
  }
  #pragma unroll
  for (int tm = 0; tm < 2; ++tm)
    #pragma unroll
    for (int tn = 0; tn < 2; ++tn) {
      int n = col0 + nh + tn * 16 + l15;
      float bv = bias[n];
      #pragma unroll
      for (int r = 0; r < 4; ++r) {
        int m = row0 + mh + tm * 16 + (lane >> 4) * 4 + r;
        C[m * 256 + n] = f2b(acc[tm][tn][r] + bv);
      }
    }
}

// ---------------------------------------------------------------------------
// K4: fused SwiGLU FFN v4 — no-duplication wave split + raw lgkm-only barrier.
// 64 rows/block, 4 waves. Per 64-e chunk (16 chunks):
//   stage1: wave w owns e-rows [e0+16w, e0+16w+16), ALL 64 m-rows.
//           Weights direct global->VGPR (A-operand, swapped mfma) -> H^T tile;
//           biases folded into MFMA C-init; cvtpk pack; b64 Hs[p] write.
//   barrier: s_waitcnt lgkmcnt(0) + raw s_barrier — NO vmcnt drain, so
//           weight loads stay in flight across it (only LDS crosses waves).
//   stage2: wave w owns n-cols [64w, 64w+64), reads Hs[p], W3 direct->VGPR,
//           oacc[4][4] accumulates across all chunks (b3 in C-init).
// Hs double-buffered -> exactly ONE barrier per chunk (16/block vs 160).
// LDS 52224B -> 3 blocks/CU; lb(256,3) caps VGPR at 170 (est. peak ~165).
// ---------------------------------------------------------------------------
__global__ __launch_bounds__(256, 3) void k_ffn(
    const short* __restrict__ x1bp,
    const short* __restrict__ W1t, const short* __restrict__ W2t,
    const short* __restrict__ W3t,
    const float* __restrict__ b1, const float* __restrict__ b2,
    const float* __restrict__ b3, const float* __restrict__ alpha,
    float* __restrict__ out)
{
  __shared__ __align__(16) short As[64 * 264];     // 33792 B
  __shared__ __align__(16) short Hs[2][64 * 72];   // 2 x 9216 B
  int row0 = blockIdx.x * 64;
  int tid = threadIdx.x, lane = tid & 63, w = tid >> 6;
  int l15 = lane & 15, g = lane >> 4;
  // ---- stage A (64x256) into LDS ----
  #pragma unroll
  for (int it = 0; it < 8; ++it) {
    int idx = it * 256 + tid;
    int rw = idx >> 5, ch = (idx & 31) * 8;
    *(bf16x8*)&As[rw * 264 + ch] = *(const bf16x8*)&x1bp[(size_t)(row0 + rw) * 256 + ch];
  }
  // ---- oacc init with b3 (wave's n-range = [64w, 64w+64)) ----
  f32x4 oacc[4][4];
  #pragma unroll
  for (int tn = 0; tn < 4; ++tn) {
    float bb = b3[w * 64 + tn * 16 + l15];
    #pragma unroll
    for (int tm = 0; tm < 4; ++tm) oacc[tm][tn] = (f32x4){bb, bb, bb, bb};
  }
  __syncthreads();
  int p = 0;
  for (int ec = 0; ec < 16; ++ec) {
    int e0 = ec * 64;
    int ew = e0 + w * 16;                 // wave's 16 e-rows
    // h init with b1/b2 (swapped layout: C rows = e = ew + g*4 + r)
    float4 c1 = *(const float4*)&b1[ew + g * 4];
    float4 c2 = *(const float4*)&b2[ew + g * 4];
    f32x4 h1[4], h2[4];
    #pragma unroll
    for (int tm = 0; tm < 4; ++tm) {
      h1[tm] = (f32x4){c1.x, c1.y, c1.z, c1.w};
      h2[tm] = (f32x4){c2.x, c2.y, c2.z, c2.w};
    }
    // ---- stage1: weights direct to regs, A from LDS ----
    #pragma unroll
    for (int kk = 0; kk < 8; ++kk) {
      bf16x8 w1f = *(const bf16x8*)&W1t[(size_t)(ew + l15) * 256 + kk * 32 + g * 8];
      bf16x8 w2f = *(const bf16x8*)&W2t[(size_t)(ew + l15) * 256 + kk * 32 + g * 8];
      #pragma unroll
      for (int tm = 0; tm < 4; ++tm) {
        bf16x8 af = *(const bf16x8*)&As[(tm * 16 + l15) * 264 + kk * 32 + g * 8];
        h1[tm] = mfma16(w1f, af, h1[tm]);   // swapped: C rows = e, cols = m
        h2[tm] = mfma16(w2f, af, h2[tm]);
      }
    }
    // ---- silu(h1)*h2 -> Hs[p] (lane holds 4 consecutive e for col m) ----
    #pragma unroll
    for (int tm = 0; tm < 4; ++tm) {
      int m = tm * 16 + l15;
      float a0 = h1[tm][0], a1 = h1[tm][1], a2 = h1[tm][2], a3 = h1[tm][3];
      float v0 = a0 * h2[tm][0] * sigf(a0);
      float v1 = a1 * h2[tm][1] * sigf(a1);
      float v2 = a2 * h2[tm][2] * sigf(a2);
      float v3 = a3 * h2[tm][3] * sigf(a3);
      uint2 pk;
      pk.x = cvtpk(v0, v1);
      pk.y = cvtpk(v2, v3);
      *(uint2*)&Hs[p][m * 72 + w * 16 + g * 4] = pk;
    }
    // ---- raw barrier: drain LDS only; global weight loads stay in flight ----
    asm volatile("s_waitcnt lgkmcnt(0)" ::: "memory");
    __builtin_amdgcn_sched_barrier(0);
    __builtin_amdgcn_s_barrier();
    __builtin_amdgcn_sched_barrier(0);
    // ---- stage2: oacc += H(64 x 64e) @ W3(64e x n-range) ----
    #pragma unroll
    for (int k2 = 0; k2 < 2; ++k2) {
      bf16x8 hf[4];
      #pragma unroll
      for (int tm = 0; tm < 4; ++tm)
        hf[tm] = *(const bf16x8*)&Hs[p][(tm * 16 + l15) * 72 + k2 * 32 + g * 8];
      #pragma unroll
      for (int tn = 0; tn < 4; ++tn) {
        bf16x8 w3f = *(const bf16x8*)&W3t[(size_t)(w * 64 + tn * 16 + l15) * 1024 + e0 + k2 * 32 + g * 8];
        #pragma unroll
        for (int tm = 0; tm < 4; ++tm)
          oacc[tm][tn] = mfma16(hf[tm], w3f, oacc[tm][tn]);
      }
    }
    p ^= 1;
  }
  // ---- final out write ----
  float sa = sigf(alpha[0]);
  #pragma unroll
  for (int tn = 0; tn < 4; ++tn) {
    int n = w * 64 + tn * 16 + l15;
    #pragma unroll
    for (int tm = 0; tm < 4; ++tm)
      #pragma unroll
      for (int r = 0; r < 4; ++r) {
        int m = row0 + tm * 16 + g * 4 + r;
        __builtin_nontemporal_store(sa * oacc[tm][tn][r], &out[(size_t)m * 256 + n]);
      }
  }
}

// ---------------------------------------------------------------------------
// K5: attention pass 1 (round-0 version). One block per (b,t,h). Row softmax
// P1 over r, v1[r][d] = sum_n P1[n][r]*xv[n][d], plus online column max/sum.
// Threads: r = tid&31, nl = tid>>5 (8 n-rows per iter, 125 iters).
// ---------------------------------------------------------------------------
__global__ __launch_bounds__(256) void k_attn1(
    const short* __restrict__ attnb, const short* __restrict__ xvb,
    float* __restrict__ v1buf, float* __restrict__ colmax, float* __restrict__ colsum)
{
  __shared__ float xr[8][32];
  __shared__ float red[8][32][32];
  __shared__ float mred[8][32], sred[8][32];
  int gid = blockIdx.x;            // bt*8 + h
  int bt = gid >> 3, h = gid & 7;
  int tid = threadIdx.x, r = tid & 31, nl = tid >> 5;
  int base = bt * NSEQ;
  float accd[32];
  #pragma unroll
  for (int d = 0; d < 32; ++d) accd[d] = 0.f;
  float mrun = -1e30f, srun = 0.f;
  for (int it = 0; it < 125; ++it) {
    int tok = base + it * 8 + nl;
    float a = b2f(attnb[tok * 256 + h * 32 + r]);
    float rmax = a;
    #pragma unroll
    for (int mm = 16; mm > 0; mm >>= 1) rmax = fmaxf(rmax, __shfl_xor(rmax, mm));
    float ea = __expf(a - rmax);
    float rsum = ea;
    #pragma unroll
    for (int mm = 16; mm > 0; mm >>= 1) rsum += __shfl_xor(rsum, mm);
    float p1 = ea / rsum;
    float nm = fmaxf(mrun, a);                       // online col stats
    srun = srun * __expf(mrun - nm) + __expf(a - nm);
    mrun = nm;
    xr[nl][r] = b2f(xvb[tok * 256 + h * 32 + r]);
    __syncthreads();
    #pragma unroll
    for (int d = 0; d < 32; ++d) accd[d] += p1 * xr[nl][d];
    __syncthreads();
  }
  #pragma unroll
  for (int d = 0; d < 32; ++d) red[nl][r][d] = accd[d];
  mred[nl][r] = mrun; sred[nl][r] = srun;
  __syncthreads();
  for (int s = 4; s > 0; s >>= 1) {
    if (nl < s)
      #pragma unroll
      for (int d = 0; d < 32; ++d) red[nl][r][d] += red[nl + s][r][d];
    __syncthreads();
  }
  if (nl == 0) {
    for (int d = 0; d < 32; ++d) v1buf[gid * 1024 + r * 32 + d] = red[0][r][d];
    float Mv = -1e30f;
    for (int j = 0; j < 8; ++j) Mv = fmaxf(Mv, mred[j][r]);
    float Sv = 0.f;
    for (int j = 0; j < 8; ++j) Sv += sred[j][r] * __expf(mred[j][r] - Mv);
    colmax[gid * 32 + r] = Mv;
    colsum[gid * 32 + r] = Sv;
  }
}

// ---------------------------------------------------------------------------
// K6: attention pass 2 + final blend (round-0 version).
// v2[n][d] = sum_r P2[n][r]*v1[r][d]; out += sig(beta)*(sig(mha_a)*xv + sig(mha_b)*v2)
// One block per (bt, chunk-of-100-tokens); thread = output column c = h*32+d.
// ---------------------------------------------------------------------------
__global__ __launch_bounds__(256) void k_attn2(
    const short* __restrict__ attnb, const short* __restrict__ xvb,
    const float* __restrict__ v1buf, const float* __restrict__ colmax,
    const float* __restrict__ colsum, const float* __restrict__ mha_alpha,
    const float* __restrict__ mha_beta, const float* __restrict__ beta,
    float* __restrict__ out)
{
  __shared__ float v1s[8 * 1024];
  __shared__ float cms[256], css[256], p2s[256];
  __shared__ float sas[8], sbs[8];
  int bt = blockIdx.x, chunk = blockIdx.y;
  int tid = threadIdx.x;
  for (int j = 0; j < 32; ++j) v1s[tid * 32 + j] = v1buf[bt * 8192 + tid * 32 + j];
  cms[tid] = colmax[bt * 256 + tid];
  css[tid] = colsum[bt * 256 + tid];
  if (tid < 8) { sas[tid] = sigf(mha_alpha[tid]); sbs[tid] = sigf(mha_beta[tid]); }
  __syncthreads();
  float sbeta = sigf(beta[0]);
  int h = tid >> 5, d = tid & 31;
  for (int tl = 0; tl < 100; ++tl) {
    int tok = bt * NSEQ + chunk * 100 + tl;
    float a = b2f(attnb[tok * 256 + tid]);
    p2s[tid] = __expf(a - cms[tid]) / css[tid];
    float xvv = b2f(xvb[tok * 256 + tid]);
    __syncthreads();
    float v2 = 0.f;
    #pragma unroll
    for (int rr = 0; rr < 32; ++rr)
      v2 += p2s[h * 32 + rr] * v1s[h * 1024 + rr * 32 + d];
    out[tok * 256 + tid] += sbeta * (sas[h] * xvv + sbs[h] * v2);
    __syncthreads();
  }
}

// ---------------------------------------------------------------------------
extern "C" void kernel_launch(void* const* d_in, const int* in_sizes, int n_in,
                              void* d_out, int out_size, void* d_ws, size_t ws_size,
                              hipStream_t stream) {
  const float* x        = (const float*)d_in[0];
  const float* z        = (const float*)d_in[1];
  const float* norm1_w  = (const float*)d_in[2];
  const float* norm2_w  = (const float*)d_in[3];
  const float* alpha    = (const float*)d_in[4];
  const float* beta     = (const float*)d_in[5];
  const float* gamma    = (const float*)d_in[6];
  const float* delta    = (const float*)d_in[7];
  const float* Wq       = (const float*)d_in[8];
  const float* bq       = (const float*)d_in[9];
  const float* key      = (const float*)d_in[10];
  const float* Wv       = (const float*)d_in[11];
  const float* bv       = (const float*)d_in[12];
  const float* mha_a    = (const float*)d_in[13];
  const float* mha_b    = (const float*)d_in[14];
  const float* W1       = (const float*)d_in[15];
  const float* b1       = (const float*)d_in[16];
  const float* W2       = (const float*)d_in[17];
  const float* b2       = (const float*)d_in[18];
  const float* W3       = (const float*)d_in[19];
  const float* b3       = (const float*)d_in[20];
  float* out = (float*)d_out;
  char* ws = (char*)d_ws;

  short* x1b   = (short*)(ws);
  short* z1b   = (short*)(ws + 49152000);
  short* xvb   = (short*)(ws + 98304000);
  short* attnb = (short*)(ws + 147456000);
  short* W1t   = (short*)(ws + 196608000);
  short* W2t   = (short*)(ws + 197132288);
  short* W3t   = (short*)(ws + 197656576);
  short* Wvt   = (short*)(ws + 198180864);
  short* Wqkt  = (short*)(ws + 198311936);
  float* bqk   = (float*)(ws + 198443008);
  float* v1buf = (float*)(ws + 198444032);
  float* colmax= (float*)(ws + 201589760);
  float* colsum= (float*)(ws + 201688064);

  hipLaunchKernelGGL(k_prep, dim3(1024), dim3(256), 0, stream,
                     Wq, bq, key, Wv, W1, W2, W3, W1t, W2t, W3t, Wvt, Wqkt, bqk);
  hipLaunchKernelGGL(k_norm, dim3(MT / 4), dim3(256), 0, stream,
                     x, z, norm1_w, norm2_w, gamma, delta, x1b, z1b);
  hipLaunchKernelGGL(k_gemm256, dim3(MT / 64, 4), dim3(256), 0, stream,
                     z1b, Wqkt, bqk, attnb);
  hipLaunchKernelGGL(k_gemm256, dim3(MT / 64, 4), dim3(256), 0, stream,
                     x1b, Wvt, bv, xvb);
  hipLaunchKernelGGL(k_ffn, dim3(MT / 64), dim3(256), 0, stream,
                     x1b, W1t, W2t, W3t, b1, b2, b3, alpha, out);
  hipLaunchKernelGGL(k_attn1, dim3(NBT * 8), dim3(256), 0, stream,
                     attnb, xvb, v1buf, colmax, colsum);
  hipLaunchKernelGGL(k_attn2, dim3(NBT, 10), dim3(256), 0, stream,
                     attnb, xvb, v1buf, colmax, colsum, mha_a, mha_b, beta, out);
}

// Round 5
// 729.298 us; speedup vs baseline: 1.4412x; 1.2122x over previous
//
#include <hip/hip_runtime.h>
#include <math.h>

// Shapes (hardcoded from reference): B=8,T=12,N=1000,D=256,H=8,R=32,HD=32,E=1024
#define MT 96000   // B*T*N tokens
#define DD 256
#define EE 1024
#define NBT 96     // B*T
#define NSEQ 1000

typedef __attribute__((ext_vector_type(8))) short bf16x8;
typedef __attribute__((ext_vector_type(4))) short bf16x4;
typedef __attribute__((ext_vector_type(4))) float f32x4;

__device__ __forceinline__ short f2b(float f) {
  union { float f; unsigned u; } v; v.f = f;
  unsigned r = (v.u + 0x7FFFu + ((v.u >> 16) & 1u)) >> 16;
  return (short)r;
}
__device__ __forceinline__ float b2f(short s) {
  union { unsigned u; float f; } v; v.u = ((unsigned)(unsigned short)s) << 16;
  return v.f;
}
__device__ __forceinline__ float sigf(float x) { return 1.f / (1.f + __expf(-x)); }
__device__ __forceinline__ f32x4 mfma16(bf16x8 a, bf16x8 b, f32x4 c) {
  return __builtin_amdgcn_mfma_f32_16x16x32_bf16(a, b, c, 0, 0, 0);
}
// packed f32x2 -> bf16x2 (RNE), single VALU inst
__device__ __forceinline__ unsigned cvtpk(float lo, float hi) {
  unsigned r;
  asm("v_cvt_pk_bf16_f32 %0, %1, %2" : "=v"(r) : "v"(lo), "v"(hi));
  return r;
}
// async global->LDS DMA: 64 lanes x 16B = 1KB per call; LDS dest is
// wave-uniform base + lane*16; global src is per-lane.
__device__ __forceinline__ void gl_lds16(const short* gp, short* lp) {
  __builtin_amdgcn_global_load_lds(
      (const __attribute__((address_space(1))) void*)gp,
      (__attribute__((address_space(3))) void*)lp, 16, 0, 0);
}

// ---------------------------------------------------------------------------
// K0: weight prep. Transposed bf16 weights ([out][in] so B-fragments are 16B
// contiguous k-octets), plus fused Wqk = (Wq . key)/sqrt(HD) and bqk.
// ---------------------------------------------------------------------------
__global__ __launch_bounds__(256) void k_prep(
    const float* __restrict__ Wq, const float* __restrict__ bq,
    const float* __restrict__ key, const float* __restrict__ Wv,
    const float* __restrict__ W1, const float* __restrict__ W2,
    const float* __restrict__ W3,
    short* __restrict__ W1t, short* __restrict__ W2t, short* __restrict__ W3t,
    short* __restrict__ Wvt, short* __restrict__ Wqkt, float* __restrict__ bqk)
{
  int i = blockIdx.x * 256 + threadIdx.x;   // 0 .. 262143
  { int e = i >> 8, c = i & 255;            // W1t/W2t: [e][c]
    W1t[i] = f2b(W1[c * EE + e]);
    W2t[i] = f2b(W2[c * EE + e]); }
  { int n = i >> 10, e = i & 1023;          // W3t: [n][e]
    W3t[i] = f2b(W3[e * DD + n]); }
  if (i < 65536) {
    int n = i >> 8, c = i & 255;
    Wvt[i] = f2b(Wv[c * DD + n]);           // Wvt: [n][c]
    int h = n >> 5, r = n & 31;
    float acc = 0.f;
    for (int d = 0; d < 32; ++d)
      acc += Wq[c * DD + h * 32 + d] * key[(r * 8 + h) * 32 + d];
    Wqkt[i] = f2b(acc * 0.17677669529663687f);  // 1/sqrt(32)
  }
  if (i < 256) {
    int h = i >> 5, r = i & 31;
    float acc = 0.f;
    for (int d = 0; d < 32; ++d)
      acc += bq[h * 32 + d] * key[(r * 8 + h) * 32 + d];
    bqk[i] = acc * 0.17677669529663687f;
  }
}

// ---------------------------------------------------------------------------
// K1: fused RMSNorm: x1 = rms(x)*w1 ; z1 = rms(sg*x1 + sd*z)*w2. bf16 out.
// One wave per token (256 elems = float4/lane).
// ---------------------------------------------------------------------------
__global__ __launch_bounds__(256) void k_norm(
    const float* __restrict__ x, const float* __restrict__ z,
    const float* __restrict__ nw1, const float* __restrict__ nw2,
    const float* __restrict__ gamma, const float* __restrict__ delta,
    short* __restrict__ x1bp, short* __restrict__ z1bp)
{
  int tok = blockIdx.x * 4 + (threadIdx.x >> 6);
  int lane = threadIdx.x & 63;
  size_t rbase = (size_t)tok * DD;
  float4 xv = ((const float4*)(x + rbase))[lane];
  float ss = xv.x*xv.x + xv.y*xv.y + xv.z*xv.z + xv.w*xv.w;
  #pragma unroll
  for (int mm = 1; mm < 64; mm <<= 1) ss += __shfl_xor(ss, mm);
  float inv = rsqrtf(ss * 0.00390625f + 1e-6f);
  float4 wv = ((const float4*)nw1)[lane];
  float xa = xv.x * inv * wv.x, xb = xv.y * inv * wv.y,
        xc = xv.z * inv * wv.z, xd = xv.w * inv * wv.w;
  bf16x4 xo = { f2b(xa), f2b(xb), f2b(xc), f2b(xd) };
  ((bf16x4*)(x1bp + rbase))[lane] = xo;
  float sg = sigf(gamma[0]), sd = sigf(delta[0]);
  float4 zv = ((const float4*)(z + rbase))[lane];
  float t0 = sg*xa + sd*zv.x, t1 = sg*xb + sd*zv.y,
        t2 = sg*xc + sd*zv.z, t3 = sg*xd + sd*zv.w;
  float s2 = t0*t0 + t1*t1 + t2*t2 + t3*t3;
  #pragma unroll
  for (int mm = 1; mm < 64; mm <<= 1) s2 += __shfl_xor(s2, mm);
  float inv2 = rsqrtf(s2 * 0.00390625f + 1e-6f);
  float4 w2v = ((const float4*)nw2)[lane];
  bf16x4 zo = { f2b(t0*inv2*w2v.x), f2b(t1*inv2*w2v.y),
                f2b(t2*inv2*w2v.z), f2b(t3*inv2*w2v.w) };
  ((bf16x4*)(z1bp + rbase))[lane] = zo;
}

// ---------------------------------------------------------------------------
// K2/K3: C_bf16[MT,256] = A_bf16[MT,256] @ Bt^T + bias. Bt is [256][256] in
// [n][k] layout. 64x64 tile, 4 waves each 32x32 (2x2 MFMA tiles).
// ---------------------------------------------------------------------------
__global__ __launch_bounds__(256) void k_gemm256(
    const short* __restrict__ A, const short* __restrict__ Bt,
    const float* __restrict__ bias, short* __restrict__ C)
{
  __shared__ __align__(16) short As[64 * 40];  // +8 pad: 2-way-at-worst banks
  __shared__ __align__(16) short Bs[64 * 40];
  int row0 = blockIdx.x * 64, col0 = blockIdx.y * 64;
  int tid = threadIdx.x, lane = tid & 63, w = tid >> 6;
  int mh = (w & 1) * 32, nh = (w >> 1) * 32;
  int l15 = lane & 15, ko = (lane >> 4) * 8;
  int lrow = tid >> 2, lch = (tid & 3) * 8;
  f32x4 acc[2][2] = {};
  for (int k0 = 0; k0 < 256; k0 += 32) {
    *(bf16x8*)&As[lrow * 40 + lch] = *(const bf16x8*)&A[(row0 + lrow) * 256 + k0 + lch];
    *(bf16x8*)&Bs[lrow * 40 + lch] = *(const bf16x8*)&Bt[(col0 + lrow) * 256 + k0 + lch];
    __syncthreads();
    bf16x8 af[2], bfr[2];
    #pragma unroll
    for (int t = 0; t < 2; ++t) {
      af[t]  = *(const bf16x8*)&As[(mh + t * 16 + l15) * 40 + ko];
      bfr[t] = *(const bf16x8*)&Bs[(nh + t * 16 + l15) * 40 + ko];
    }
    #pragma unroll
    for (int tm = 0; tm < 2; ++tm)
      #pragma unroll
      for (int tn = 0; tn < 2; ++tn)
        acc[tm][tn] = mfma16(af[tm], bfr[tn], acc[tm][tn]);
    __syncthreads();
  }
  #pragma unroll
  for (int tm = 0; tm < 2; ++tm)
    #pragma unroll
    for (int tn = 0; tn < 2; ++tn) {
      int n = col0 + nh + tn * 16 + l15;
      float bv = bias[n];
      #pragma unroll
      for (int r = 0; r < 4; ++r) {
        int m = row0 + mh + tm * 16 + (lane >> 4) * 4 + r;
        C[m * 256 + n] = f2b(acc[tm][tn][r] + bv);
      }
    }
}

// ---------------------------------------------------------------------------
// K4: fused SwiGLU FFN v5.1 — global_load_lds weight streaming, counted vmcnt.
// 64 rows/block, 4 waves. Wave-private weights stream through a 4-slot x 2KB
// LDS ring via DMA (zero VGPR cost). Per 64-e chunk: 12 slices of 2KB
// (8x W1||W2 per-kk, 4x W3-half), consumed in issue order, always <=8 DMA ops
// in flight -> waits are vmcnt(6)/vmcnt(4), NEVER 0, and never cross-wave
// (weights are private). Only Hs crosses waves: 2 raw lgkm-only s_barriers
// per chunk. ec=15 wraps prefetch to ec=0 (keeps counts static); a FINAL
// vmcnt(0) drain before the epilogue guarantees no DMA is outstanding at
// s_endpgm (r4 crash fix: dangling LDS-DMA past kernel end is a fault).
// WR slot layout [16r x 64B] would be 8-way bank-conflicted on b128 reads;
// source-octet XOR pre-swizzle (k = (row>>1)&3) + same XOR on read -> 4-way.
// As: stride-256 + granule XOR swizzle (c ^= row&7) = min-aliasing b128.
// b1/b2 staged as bf16 in LDS (no vmem ops inside the loop); b3 in C-init.
// LDS = 32K(As)+9K(Hs)+32K(ring)+4K(Bb) = 77KB -> 2 blocks/CU; lb(256,2).
// ---------------------------------------------------------------------------
__global__ __launch_bounds__(256, 2) void k_ffn(
    const short* __restrict__ x1bp,
    const short* __restrict__ W1t, const short* __restrict__ W2t,
    const short* __restrict__ W3t,
    const float* __restrict__ b1, const float* __restrict__ b2,
    const float* __restrict__ b3, const float* __restrict__ alpha,
    float* __restrict__ out)
{
  __shared__ __align__(16) short As[64 * 256];   // 32768 B, XOR-swizzled granules
  __shared__ __align__(16) short Hs[64 * 72];    // 9216 B
  __shared__ __align__(16) short WR[4 * 4096];   // 4 waves x 4 slots x 2KB
  __shared__ __align__(16) short Bb[2048];       // b1,b2 as bf16
  int row0 = blockIdx.x * 64;
  int tid = threadIdx.x, lane = tid & 63, w = tid >> 6;
  int l15 = lane & 15, g = lane >> 4;
  int swz = l15 & 7;
  int w16 = w * 16;
  int wb = w * 4096;                   // ring base (shorts)
  int lr = lane >> 2;                  // DMA source row
  // DMA source col-octet, XOR pre-swizzled so linear LDS = swizzled data:
  int lc = (((lane & 3) ^ ((lane >> 3) & 3)) * 8);
  int rsw = (l15 >> 1) & 3;            // read-side XOR key (= (row>>1)&3)

  // ---- stage A (64x256) into As with granule swizzle ----
  #pragma unroll
  for (int it = 0; it < 8; ++it) {
    int idx = it * 256 + tid;
    int rw = idx >> 5, c = idx & 31;
    bf16x8 v = __builtin_nontemporal_load(
        (const bf16x8*)&x1bp[(size_t)(row0 + rw) * 256 + c * 8]);
    *(bf16x8*)&As[rw * 256 + ((c ^ (rw & 7)) * 8)] = v;
  }
  // ---- stage b1/b2 as bf16 ----
  {
    float4 v1 = ((const float4*)b1)[tid];
    float4 v2 = ((const float4*)b2)[tid];
    bf16x4 p1 = { f2b(v1.x), f2b(v1.y), f2b(v1.z), f2b(v1.w) };
    bf16x4 p2 = { f2b(v2.x), f2b(v2.y), f2b(v2.z), f2b(v2.w) };
    *(bf16x4*)&Bb[tid * 4] = p1;
    *(bf16x4*)&Bb[1024 + tid * 4] = p2;
  }
  // ---- oacc init with b3 (wave's n-range = [64w, 64w+64)) ----
  f32x4 oacc[4][4];
  #pragma unroll
  for (int tn = 0; tn < 4; ++tn) {
    float bb = b3[w * 64 + tn * 16 + l15];
    #pragma unroll
    for (int tm = 0; tm < 4; ++tm) oacc[tm][tn] = (f32x4){bb, bb, bb, bb};
  }
  __syncthreads();   // drains vmcnt to 0: clean counting state

  // ---- prologue: issue ec0 S1 slices kk=0..3 into slots 0..3 ----
  #pragma unroll
  for (int s = 0; s < 4; ++s) {
    gl_lds16(W1t + (size_t)(w16 + lr) * 256 + s * 32 + lc, &WR[wb + s * 1024]);
    gl_lds16(W2t + (size_t)(w16 + lr) * 256 + s * 32 + lc, &WR[wb + s * 1024 + 512]);
  }

  for (int ec = 0; ec < 16; ++ec) {
    int e0 = ec * 64;
    int e0n = ((ec + 1) & 15) * 64;    // wrap keeps vmcnt accounting uniform
    int ew = e0 + w16;
    // h accumulators init from Bb (C rows = e = ew + g*4 + r)
    bf16x4 c1b = *(const bf16x4*)&Bb[ew + g * 4];
    bf16x4 c2b = *(const bf16x4*)&Bb[1024 + ew + g * 4];
    f32x4 i1 = { b2f(c1b[0]), b2f(c1b[1]), b2f(c1b[2]), b2f(c1b[3]) };
    f32x4 i2 = { b2f(c2b[0]), b2f(c2b[1]), b2f(c2b[2]), b2f(c2b[3]) };
    f32x4 h1[4], h2[4];
    #pragma unroll
    for (int tm = 0; tm < 4; ++tm) { h1[tm] = i1; h2[tm] = i2; }
    // ---- stage1: 8 k-phases; slice kk from slot kk&3, then refill slot ----
    #pragma unroll
    for (int kk = 0; kk < 8; ++kk) {
      int slot = kk & 3;
      asm volatile("s_waitcnt vmcnt(6)" ::: "memory");   // slice kk resident
      bf16x8 w1f = *(const bf16x8*)&WR[wb + slot * 1024 + l15 * 32 + ((0 ^ rsw) * 8)
                                       + ((g ^ rsw) * 8) - ((0 ^ rsw) * 8)];
      bf16x8 w2f = *(const bf16x8*)&WR[wb + slot * 1024 + 512 + l15 * 32 + ((g ^ rsw) * 8)];
      int ac = ((kk * 4 + g) ^ swz) * 8;
      bf16x8 a0 = *(const bf16x8*)&As[(l15) * 256 + ac];
      bf16x8 a1 = *(const bf16x8*)&As[(16 + l15) * 256 + ac];
      bf16x8 a2 = *(const bf16x8*)&As[(32 + l15) * 256 + ac];
      bf16x8 a3 = *(const bf16x8*)&As[(48 + l15) * 256 + ac];
      asm volatile("s_waitcnt lgkmcnt(0)" ::: "memory"); // slot reads done -> reusable
      if (kk < 4) {          // refill with S1 slice kk+4 (same ec)
        gl_lds16(W1t + (size_t)(ew + lr) * 256 + (kk + 4) * 32 + lc,
                 &WR[wb + slot * 1024]);
        gl_lds16(W2t + (size_t)(ew + lr) * 256 + (kk + 4) * 32 + lc,
                 &WR[wb + slot * 1024 + 512]);
      } else {               // refill with W3 slice: k2=(kk-4)>>1, nh=kk&1
        int k2i = (kk - 4) >> 1, nh = kk & 1;
        const short* g3 = W3t + (size_t)(w * 64 + nh * 32 + lr) * 1024
                          + e0 + k2i * 32 + lc;
        gl_lds16(g3, &WR[wb + slot * 1024]);
        gl_lds16(g3 + 16 * 1024, &WR[wb + slot * 1024 + 512]);
      }
      h1[0] = mfma16(w1f, a0, h1[0]); h2[0] = mfma16(w2f, a0, h2[0]);
      h1[1] = mfma16(w1f, a1, h1[1]); h2[1] = mfma16(w2f, a1, h2[1]);
      h1[2] = mfma16(w1f, a2, h1[2]); h2[2] = mfma16(w2f, a2, h2[2]);
      h1[3] = mfma16(w1f, a3, h1[3]); h2[3] = mfma16(w2f, a3, h2[3]);
    }
    // ---- silu(h1)*h2 -> Hs (lane holds 4 consecutive e for col m) ----
    #pragma unroll
    for (int tm = 0; tm < 4; ++tm) {
      int m = tm * 16 + l15;
      float a0 = h1[tm][0], a1 = h1[tm][1], a2 = h1[tm][2], a3 = h1[tm][3];
      float v0 = a0 * h2[tm][0] * sigf(a0);
      float v1 = a1 * h2[tm][1] * sigf(a1);
      float v2 = a2 * h2[tm][2] * sigf(a2);
      float v3 = a3 * h2[tm][3] * sigf(a3);
      uint2 pk;
      pk.x = cvtpk(v0, v1);
      pk.y = cvtpk(v2, v3);
      *(uint2*)&Hs[m * 72 + w16 + g * 4] = pk;
    }
    // ---- barrier 1: Hs writes visible (lgkm-only; DMA stays in flight) ----
    asm volatile("s_waitcnt lgkmcnt(0)" ::: "memory");
    __builtin_amdgcn_sched_barrier(0);
    __builtin_amdgcn_s_barrier();
    __builtin_amdgcn_sched_barrier(0);
    // ---- stage2: 2 e-half phases ----
    #pragma unroll
    for (int k2 = 0; k2 < 2; ++k2) {
      asm volatile("s_waitcnt vmcnt(4)" ::: "memory");   // W3 halves resident
      bf16x8 hf[4];
      #pragma unroll
      for (int tm = 0; tm < 4; ++tm)
        hf[tm] = *(const bf16x8*)&Hs[(tm * 16 + l15) * 72 + k2 * 32 + g * 8];
      bf16x8 w3f[4];
      #pragma unroll
      for (int tn = 0; tn < 4; ++tn)
        w3f[tn] = *(const bf16x8*)&WR[wb + (k2 * 2 + (tn >> 1)) * 1024
                                     + (tn & 1) * 512 + l15 * 32 + ((g ^ rsw) * 8)];
      asm volatile("s_waitcnt lgkmcnt(0)" ::: "memory"); // slots reusable
      // prefetch next-ec S1 slices (k2*2), (k2*2+1) into the freed slots
      gl_lds16(W1t + (size_t)(e0n + w16 + lr) * 256 + (k2 * 2) * 32 + lc,
               &WR[wb + (k2 * 2) * 1024]);
      gl_lds16(W2t + (size_t)(e0n + w16 + lr) * 256 + (k2 * 2) * 32 + lc,
               &WR[wb + (k2 * 2) * 1024 + 512]);
      gl_lds16(W1t + (size_t)(e0n + w16 + lr) * 256 + (k2 * 2 + 1) * 32 + lc,
               &WR[wb + (k2 * 2 + 1) * 1024]);
      gl_lds16(W2t + (size_t)(e0n + w16 + lr) * 256 + (k2 * 2 + 1) * 32 + lc,
               &WR[wb + (k2 * 2 + 1) * 1024 + 512]);
      #pragma unroll
      for (int tn = 0; tn < 4; ++tn)
        #pragma unroll
        for (int tm = 0; tm < 4; ++tm)
          oacc[tm][tn] = mfma16(hf[tm], w3f[tn], oacc[tm][tn]);
    }
    // ---- barrier 2: Hs reads done before next chunk overwrites ----
    __builtin_amdgcn_sched_barrier(0);
    __builtin_amdgcn_s_barrier();
    __builtin_amdgcn_sched_barrier(0);
  }
  // ---- FINAL DRAIN: no LDS-DMA may be outstanding at s_endpgm ----
  asm volatile("s_waitcnt vmcnt(0)" ::: "memory");
  // ---- final out write (nt) ----
  float sa = sigf(alpha[0]);
  #pragma unroll
  for (int tn = 0; tn < 4; ++tn) {
    int n = w * 64 + tn * 16 + l15;
    #pragma unroll
    for (int tm = 0; tm < 4; ++tm)
      #pragma unroll
      for (int r = 0; r < 4; ++r) {
        int m = row0 + tm * 16 + g * 4 + r;
        __builtin_nontemporal_store(sa * oacc[tm][tn][r], &out[(size_t)m * 256 + n]);
      }
  }
}

// ---------------------------------------------------------------------------
// K5: attention pass 1. One block per (b,t,h). Row softmax P1 over r,
// v1[r][d] = sum_n P1[n][r]*xv[n][d], plus online column (over n) max/sum.
// All xr traffic is within one half-wave (writer and reader share nl), and
// same-wave DS ops are processed in order -> NO in-loop barriers needed.
// ---------------------------------------------------------------------------
__global__ __launch_bounds__(256) void k_attn1(
    const short* __restrict__ attnb, const short* __restrict__ xvb,
    float* __restrict__ v1buf, float* __restrict__ colmax, float* __restrict__ colsum)
{
  __shared__ float xr[8][32];
  __shared__ float red[8][32][32];
  __shared__ float mred[8][32], sred[8][32];
  int gid = blockIdx.x;            // bt*8 + h
  int bt = gid >> 3, h = gid & 7;
  int tid = threadIdx.x, r = tid & 31, nl = tid >> 5;
  int base = bt * NSEQ;
  float accd[32];
  #pragma unroll
  for (int d = 0; d < 32; ++d) accd[d] = 0.f;
  float mrun = -1e30f, srun = 0.f;
  for (int it = 0; it < 125; ++it) {
    int tok = base + it * 8 + nl;
    float a = b2f(attnb[(size_t)tok * 256 + h * 32 + r]);
    float rmax = a;
    #pragma unroll
    for (int mm = 16; mm > 0; mm >>= 1) rmax = fmaxf(rmax, __shfl_xor(rmax, mm));
    float ea = __expf(a - rmax);
    float rsum = ea;
    #pragma unroll
    for (int mm = 16; mm > 0; mm >>= 1) rsum += __shfl_xor(rsum, mm);
    float p1 = ea / rsum;
    float nm = fmaxf(mrun, a);                       // online col stats
    srun = srun * __expf(mrun - nm) + __expf(a - nm);
    mrun = nm;
    xr[nl][r] = b2f(xvb[(size_t)tok * 256 + h * 32 + r]);
    // same half-wave write->read: in-order DS pipeline, no barrier
    #pragma unroll
    for (int d = 0; d < 32; ++d) accd[d] += p1 * xr[nl][d];
  }
  #pragma unroll
  for (int d = 0; d < 32; ++d) red[nl][r][d] = accd[d];
  mred[nl][r] = mrun; sred[nl][r] = srun;
  __syncthreads();
  for (int s = 4; s > 0; s >>= 1) {
    if (nl < s)
      #pragma unroll
      for (int d = 0; d < 32; ++d) red[nl][r][d] += red[nl + s][r][d];
    __syncthreads();
  }
  if (nl == 0) {
    for (int d = 0; d < 32; ++d) v1buf[gid * 1024 + r * 32 + d] = red[0][r][d];
    float Mv = -1e30f;
    for (int j = 0; j < 8; ++j) Mv = fmaxf(Mv, mred[j][r]);
    float Sv = 0.f;
    for (int j = 0; j < 8; ++j) Sv += sred[j][r] * __expf(mred[j][r] - Mv);
    colmax[gid * 32 + r] = Mv;
    colsum[gid * 32 + r] = Sv;
  }
}

// ---------------------------------------------------------------------------
// K6: attention pass 2 + final blend.
// v2[n][d] = sum_r P2[n][r]*v1[r][d]; out += sig(beta)*(sig(mha_a)*xv + sig(mha_b)*v2)
// p2s traffic is within one half-wave (writer/reader share h) -> no in-loop
// barriers. v1s staged with float4; one barrier after staging only.
// ---------------------------------------------------------------------------
__global__ __launch_bounds__(256) void k_attn2(
    const short* __restrict__ attnb, const short* __restrict__ xvb,
    const float* __restrict__ v1buf, const float* __restrict__ colmax,
    const float* __restrict__ colsum, const float* __restrict__ mha_alpha,
    const float* __restrict__ mha_beta, const float* __restrict__ beta,
    float* __restrict__ out)
{
  __shared__ float v1s[8 * 1024];
  __shared__ float p2s[256];
  int bt = blockIdx.x, chunk = blockIdx.y;
  int tid = threadIdx.x;
  #pragma unroll
  for (int q = 0; q < 8; ++q)
    ((float4*)v1s)[q * 256 + tid] = ((const float4*)(v1buf + (size_t)bt * 8192))[q * 256 + tid];
  int h = tid >> 5, d = tid & 31;
  float cm  = colmax[bt * 256 + tid];
  float rcs = 1.f / colsum[bt * 256 + tid];
  float sa = sigf(mha_alpha[h]), sb = sigf(mha_beta[h]);
  float sbeta = sigf(beta[0]);
  __syncthreads();
  const float* v1p = v1s + h * 1024 + d;
  int tok0 = bt * NSEQ + chunk * 100;
  for (int tl = 0; tl < 100; ++tl) {
    int tok = tok0 + tl;
    float a = b2f(attnb[(size_t)tok * 256 + tid]);
    p2s[tid] = __expf(a - cm) * rcs;
    float xvv = b2f(xvb[(size_t)tok * 256 + tid]);
    // same half-wave write->read: in-order DS pipeline, no barrier
    float v2 = 0.f;
    #pragma unroll
    for (int rr = 0; rr < 32; ++rr)
      v2 += p2s[h * 32 + rr] * v1p[rr * 32];
    out[(size_t)tok * 256 + tid] += sbeta * (sa * xvv + sb * v2);
  }
}

// ---------------------------------------------------------------------------
extern "C" void kernel_launch(void* const* d_in, const int* in_sizes, int n_in,
                              void* d_out, int out_size, void* d_ws, size_t ws_size,
                              hipStream_t stream) {
  const float* x        = (const float*)d_in[0];
  const float* z        = (const float*)d_in[1];
  const float* norm1_w  = (const float*)d_in[2];
  const float* norm2_w  = (const float*)d_in[3];
  const float* alpha    = (const float*)d_in[4];
  const float* beta     = (const float*)d_in[5];
  const float* gamma    = (const float*)d_in[6];
  const float* delta    = (const float*)d_in[7];
  const float* Wq       = (const float*)d_in[8];
  const float* bq       = (const float*)d_in[9];
  const float* key      = (const float*)d_in[10];
  const float* Wv       = (const float*)d_in[11];
  const float* bv       = (const float*)d_in[12];
  const float* mha_a    = (const float*)d_in[13];
  const float* mha_b    = (const float*)d_in[14];
  const float* W1       = (const float*)d_in[15];
  const float* b1       = (const float*)d_in[16];
  const float* W2       = (const float*)d_in[17];
  const float* b2       = (const float*)d_in[18];
  const float* W3       = (const float*)d_in[19];
  const float* b3       = (const float*)d_in[20];
  float* out = (float*)d_out;
  char* ws = (char*)d_ws;

  short* x1b   = (short*)(ws);
  short* z1b   = (short*)(ws + 49152000);
  short* xvb   = (short*)(ws + 98304000);
  short* attnb = (short*)(ws + 147456000);
  short* W1t   = (short*)(ws + 196608000);
  short* W2t   = (short*)(ws + 197132288);
  short* W3t   = (short*)(ws + 197656576);
  short* Wvt   = (short*)(ws + 198180864);
  short* Wqkt  = (short*)(ws + 198311936);
  float* bqk   = (float*)(ws + 198443008);
  float* v1buf = (float*)(ws + 198444032);
  float* colmax= (float*)(ws + 201589760);
  float* colsum= (float*)(ws + 201688064);

  hipLaunchKernelGGL(k_prep, dim3(1024), dim3(256), 0, stream,
                     Wq, bq, key, Wv, W1, W2, W3, W1t, W2t, W3t, Wvt, Wqkt, bqk);
  hipLaunchKernelGGL(k_norm, dim3(MT / 4), dim3(256), 0, stream,
                     x, z, norm1_w, norm2_w, gamma, delta, x1b, z1b);
  hipLaunchKernelGGL(k_gemm256, dim3(MT / 64, 4), dim3(256), 0, stream,
                     z1b, Wqkt, bqk, attnb);
  hipLaunchKernelGGL(k_gemm256, dim3(MT / 64, 4), dim3(256), 0, stream,
                     x1b, Wvt, bv, xvb);
  hipLaunchKernelGGL(k_ffn, dim3(MT / 64), dim3(256), 0, stream,
                     x1b, W1t, W2t, W3t, b1, b2, b3, alpha, out);
  hipLaunchKernelGGL(k_attn1, dim3(NBT * 8), dim3(256), 0, stream,
                     attnb, xvb, v1buf, colmax, colsum);
  hipLaunchKernelGGL(k_attn2, dim3(NBT, 10), dim3(256), 0, stream,
                     attnb, xvb, v1buf, colmax, colsum, mha_a, mha_b, beta, out);
}

// Round 6
// 726.819 us; speedup vs baseline: 1.4461x; 1.0034x over previous
//
#include <hip/hip_runtime.h>
#include <math.h>

// Shapes (hardcoded from reference): B=8,T=12,N=1000,D=256,H=8,R=32,HD=32,E=1024
#define MT 96000   // B*T*N tokens
#define DD 256
#define EE 1024
#define NBT 96     // B*T
#define NSEQ 1000

typedef __attribute__((ext_vector_type(8))) short bf16x8;
typedef __attribute__((ext_vector_type(4))) short bf16x4;
typedef __attribute__((ext_vector_type(4))) float f32x4;

__device__ __forceinline__ short f2b(float f) {
  union { float f; unsigned u; } v; v.f = f;
  unsigned r = (v.u + 0x7FFFu + ((v.u >> 16) & 1u)) >> 16;
  return (short)r;
}
__device__ __forceinline__ float b2f(short s) {
  union { unsigned u; float f; } v; v.u = ((unsigned)(unsigned short)s) << 16;
  return v.f;
}
__device__ __forceinline__ float sigf(float x) { return 1.f / (1.f + __expf(-x)); }
__device__ __forceinline__ f32x4 mfma16(bf16x8 a, bf16x8 b, f32x4 c) {
  return __builtin_amdgcn_mfma_f32_16x16x32_bf16(a, b, c, 0, 0, 0);
}
// packed f32x2 -> bf16x2 (RNE), single VALU inst
__device__ __forceinline__ unsigned cvtpk(float lo, float hi) {
  unsigned r;
  asm("v_cvt_pk_bf16_f32 %0, %1, %2" : "=v"(r) : "v"(lo), "v"(hi));
  return r;
}
// fast f32 reciprocal (v_rcp_f32, ~1ulp) — safe for softmax denominators (>0)
__device__ __forceinline__ float frcp(float x) {
  float r;
  asm("v_rcp_f32 %0, %1" : "=v"(r) : "v"(x));
  return r;
}
// async global->LDS DMA: 64 lanes x 16B = 1KB per call; LDS dest is
// wave-uniform base + lane*16; global src is per-lane.
__device__ __forceinline__ void gl_lds16(const short* gp, short* lp) {
  __builtin_amdgcn_global_load_lds(
      (const __attribute__((address_space(1))) void*)gp,
      (__attribute__((address_space(3))) void*)lp, 16, 0, 0);
}

// ---------------------------------------------------------------------------
// K0: weight prep. Transposed bf16 weights ([out][in] so B-fragments are 16B
// contiguous k-octets), plus fused Wqk = (Wq . key)/sqrt(HD) and bqk.
// ---------------------------------------------------------------------------
__global__ __launch_bounds__(256) void k_prep(
    const float* __restrict__ Wq, const float* __restrict__ bq,
    const float* __restrict__ key, const float* __restrict__ Wv,
    const float* __restrict__ W1, const float* __restrict__ W2,
    const float* __restrict__ W3,
    short* __restrict__ W1t, short* __restrict__ W2t, short* __restrict__ W3t,
    short* __restrict__ Wvt, short* __restrict__ Wqkt, float* __restrict__ bqk)
{
  int i = blockIdx.x * 256 + threadIdx.x;   // 0 .. 262143
  { int e = i >> 8, c = i & 255;            // W1t/W2t: [e][c]
    W1t[i] = f2b(W1[c * EE + e]);
    W2t[i] = f2b(W2[c * EE + e]); }
  { int n = i >> 10, e = i & 1023;          // W3t: [n][e]
    W3t[i] = f2b(W3[e * DD + n]); }
  if (i < 65536) {
    int n = i >> 8, c = i & 255;
    Wvt[i] = f2b(Wv[c * DD + n]);           // Wvt: [n][c]
    int h = n >> 5, r = n & 31;
    float acc = 0.f;
    for (int d = 0; d < 32; ++d)
      acc += Wq[c * DD + h * 32 + d] * key[(r * 8 + h) * 32 + d];
    Wqkt[i] = f2b(acc * 0.17677669529663687f);  // 1/sqrt(32)
  }
  if (i < 256) {
    int h = i >> 5, r = i & 31;
    float acc = 0.f;
    for (int d = 0; d < 32; ++d)
      acc += bq[h * 32 + d] * key[(r * 8 + h) * 32 + d];
    bqk[i] = acc * 0.17677669529663687f;
  }
}

// ---------------------------------------------------------------------------
// K1: fused RMSNorm: x1 = rms(x)*w1 ; z1 = rms(sg*x1 + sd*z)*w2. bf16 out.
// One wave per token (256 elems = float4/lane).
// ---------------------------------------------------------------------------
__global__ __launch_bounds__(256) void k_norm(
    const float* __restrict__ x, const float* __restrict__ z,
    const float* __restrict__ nw1, const float* __restrict__ nw2,
    const float* __restrict__ gamma, const float* __restrict__ delta,
    short* __restrict__ x1bp, short* __restrict__ z1bp)
{
  int tok = blockIdx.x * 4 + (threadIdx.x >> 6);
  int lane = threadIdx.x & 63;
  size_t rbase = (size_t)tok * DD;
  float4 xv = ((const float4*)(x + rbase))[lane];
  float ss = xv.x*xv.x + xv.y*xv.y + xv.z*xv.z + xv.w*xv.w;
  #pragma unroll
  for (int mm = 1; mm < 64; mm <<= 1) ss += __shfl_xor(ss, mm);
  float inv = rsqrtf(ss * 0.00390625f + 1e-6f);
  float4 wv = ((const float4*)nw1)[lane];
  float xa = xv.x * inv * wv.x, xb = xv.y * inv * wv.y,
        xc = xv.z * inv * wv.z, xd = xv.w * inv * wv.w;
  bf16x4 xo = { f2b(xa), f2b(xb), f2b(xc), f2b(xd) };
  ((bf16x4*)(x1bp + rbase))[lane] = xo;
  float sg = sigf(gamma[0]), sd = sigf(delta[0]);
  float4 zv = ((const float4*)(z + rbase))[lane];
  float t0 = sg*xa + sd*zv.x, t1 = sg*xb + sd*zv.y,
        t2 = sg*xc + sd*zv.z, t3 = sg*xd + sd*zv.w;
  float s2 = t0*t0 + t1*t1 + t2*t2 + t3*t3;
  #pragma unroll
  for (int mm = 1; mm < 64; mm <<= 1) s2 += __shfl_xor(s2, mm);
  float inv2 = rsqrtf(s2 * 0.00390625f + 1e-6f);
  float4 w2v = ((const float4*)nw2)[lane];
  bf16x4 zo = { f2b(t0*inv2*w2v.x), f2b(t1*inv2*w2v.y),
                f2b(t2*inv2*w2v.z), f2b(t3*inv2*w2v.w) };
  ((bf16x4*)(z1bp + rbase))[lane] = zo;
}

// ---------------------------------------------------------------------------
// K2/K3: C_bf16[MT,256] = A_bf16[MT,256] @ Bt^T + bias. Bt is [256][256] in
// [n][k] layout. NEW: 64 rows x FULL 256 cols per block (grid 1500x1):
// A staged ONCE in LDS (was re-read 4x across col-blocks), weights stream
// direct global->VGPR from L2 (128KB, resident), ZERO barriers in the K-loop
// so the compiler software-pipelines the weight loads. Wave w owns n-range
// [64w,64w+64): acc[4][4], bias folded into MFMA C-init (ffn-stage2 pattern,
// layout verified by r3/r5 PASS).
// ---------------------------------------------------------------------------
__global__ __launch_bounds__(256) void k_gemm_fullN(
    const short* __restrict__ A, const short* __restrict__ Bt,
    const float* __restrict__ bias, short* __restrict__ C)
{
  __shared__ __align__(16) short As[64 * 264];
  int row0 = blockIdx.x * 64;
  int tid = threadIdx.x, lane = tid & 63, w = tid >> 6;
  int l15 = lane & 15, g = lane >> 4;
  #pragma unroll
  for (int it = 0; it < 8; ++it) {
    int idx = it * 256 + tid;
    int rw = idx >> 5, ch = (idx & 31) * 8;
    *(bf16x8*)&As[rw * 264 + ch] = *(const bf16x8*)&A[(size_t)(row0 + rw) * 256 + ch];
  }
  f32x4 acc[4][4];
  #pragma unroll
  for (int tn = 0; tn < 4; ++tn) {
    float bb = bias[w * 64 + tn * 16 + l15];
    #pragma unroll
    for (int tm = 0; tm < 4; ++tm) acc[tm][tn] = (f32x4){bb, bb, bb, bb};
  }
  __syncthreads();
  #pragma unroll
  for (int kk = 0; kk < 8; ++kk) {
    bf16x8 af[4], wf[4];
    #pragma unroll
    for (int tm = 0; tm < 4; ++tm)
      af[tm] = *(const bf16x8*)&As[(tm * 16 + l15) * 264 + kk * 32 + g * 8];
    #pragma unroll
    for (int tn = 0; tn < 4; ++tn)
      wf[tn] = *(const bf16x8*)&Bt[(size_t)(w * 64 + tn * 16 + l15) * 256 + kk * 32 + g * 8];
    #pragma unroll
    for (int tn = 0; tn < 4; ++tn)
      #pragma unroll
      for (int tm = 0; tm < 4; ++tm)
        acc[tm][tn] = mfma16(af[tm], wf[tn], acc[tm][tn]);
  }
  #pragma unroll
  for (int tn = 0; tn < 4; ++tn) {
    int n = w * 64 + tn * 16 + l15;
    #pragma unroll
    for (int tm = 0; tm < 4; ++tm)
      #pragma unroll
      for (int r = 0; r < 4; ++r) {
        int m = row0 + tm * 16 + g * 4 + r;
        C[(size_t)m * 256 + n] = f2b(acc[tm][tn][r]);
      }
  }
}

// ---------------------------------------------------------------------------
// K4: fused SwiGLU FFN v5.1 — global_load_lds weight streaming, counted vmcnt.
// (unchanged from r5 except cosmetic cleanup of a folded expression)
// 64 rows/block, 4 waves. Wave-private weights stream through a 4-slot x 2KB
// LDS ring via DMA; waits are vmcnt(6)/vmcnt(4), never 0, never cross-wave.
// Only Hs crosses waves: 2 raw lgkm-only s_barriers per chunk. Final vmcnt(0)
// drain before epilogue (no DMA outstanding at s_endpgm).
// ---------------------------------------------------------------------------
__global__ __launch_bounds__(256, 2) void k_ffn(
    const short* __restrict__ x1bp,
    const short* __restrict__ W1t, const short* __restrict__ W2t,
    const short* __restrict__ W3t,
    const float* __restrict__ b1, const float* __restrict__ b2,
    const float* __restrict__ b3, const float* __restrict__ alpha,
    float* __restrict__ out)
{
  __shared__ __align__(16) short As[64 * 256];   // 32768 B, XOR-swizzled granules
  __shared__ __align__(16) short Hs[64 * 72];    // 9216 B
  __shared__ __align__(16) short WR[4 * 4096];   // 4 waves x 4 slots x 2KB
  __shared__ __align__(16) short Bb[2048];       // b1,b2 as bf16
  int row0 = blockIdx.x * 64;
  int tid = threadIdx.x, lane = tid & 63, w = tid >> 6;
  int l15 = lane & 15, g = lane >> 4;
  int swz = l15 & 7;
  int w16 = w * 16;
  int wb = w * 4096;                   // ring base (shorts)
  int lr = lane >> 2;                  // DMA source row
  // DMA source col-octet, XOR pre-swizzled so linear LDS = swizzled data:
  int lc = (((lane & 3) ^ ((lane >> 3) & 3)) * 8);
  int rsw = (l15 >> 1) & 3;            // read-side XOR key (= (row>>1)&3)

  // ---- stage A (64x256) into As with granule swizzle ----
  #pragma unroll
  for (int it = 0; it < 8; ++it) {
    int idx = it * 256 + tid;
    int rw = idx >> 5, c = idx & 31;
    bf16x8 v = __builtin_nontemporal_load(
        (const bf16x8*)&x1bp[(size_t)(row0 + rw) * 256 + c * 8]);
    *(bf16x8*)&As[rw * 256 + ((c ^ (rw & 7)) * 8)] = v;
  }
  // ---- stage b1/b2 as bf16 ----
  {
    float4 v1 = ((const float4*)b1)[tid];
    float4 v2 = ((const float4*)b2)[tid];
    bf16x4 p1 = { f2b(v1.x), f2b(v1.y), f2b(v1.z), f2b(v1.w) };
    bf16x4 p2 = { f2b(v2.x), f2b(v2.y), f2b(v2.z), f2b(v2.w) };
    *(bf16x4*)&Bb[tid * 4] = p1;
    *(bf16x4*)&Bb[1024 + tid * 4] = p2;
  }
  // ---- oacc init with b3 (wave's n-range = [64w, 64w+64)) ----
  f32x4 oacc[4][4];
  #pragma unroll
  for (int tn = 0; tn < 4; ++tn) {
    float bb = b3[w * 64 + tn * 16 + l15];
    #pragma unroll
    for (int tm = 0; tm < 4; ++tm) oacc[tm][tn] = (f32x4){bb, bb, bb, bb};
  }
  __syncthreads();   // drains vmcnt to 0: clean counting state

  // ---- prologue: issue ec0 S1 slices kk=0..3 into slots 0..3 ----
  #pragma unroll
  for (int s = 0; s < 4; ++s) {
    gl_lds16(W1t + (size_t)(w16 + lr) * 256 + s * 32 + lc, &WR[wb + s * 1024]);
    gl_lds16(W2t + (size_t)(w16 + lr) * 256 + s * 32 + lc, &WR[wb + s * 1024 + 512]);
  }

  for (int ec = 0; ec < 16; ++ec) {
    int e0 = ec * 64;
    int e0n = ((ec + 1) & 15) * 64;    // wrap keeps vmcnt accounting uniform
    int ew = e0 + w16;
    // h accumulators init from Bb (C rows = e = ew + g*4 + r)
    bf16x4 c1b = *(const bf16x4*)&Bb[ew + g * 4];
    bf16x4 c2b = *(const bf16x4*)&Bb[1024 + ew + g * 4];
    f32x4 i1 = { b2f(c1b[0]), b2f(c1b[1]), b2f(c1b[2]), b2f(c1b[3]) };
    f32x4 i2 = { b2f(c2b[0]), b2f(c2b[1]), b2f(c2b[2]), b2f(c2b[3]) };
    f32x4 h1[4], h2[4];
    #pragma unroll
    for (int tm = 0; tm < 4; ++tm) { h1[tm] = i1; h2[tm] = i2; }
    // ---- stage1: 8 k-phases; slice kk from slot kk&3, then refill slot ----
    #pragma unroll
    for (int kk = 0; kk < 8; ++kk) {
      int slot = kk & 3;
      asm volatile("s_waitcnt vmcnt(6)" ::: "memory");   // slice kk resident
      bf16x8 w1f = *(const bf16x8*)&WR[wb + slot * 1024 + l15 * 32 + ((g ^ rsw) * 8)];
      bf16x8 w2f = *(const bf16x8*)&WR[wb + slot * 1024 + 512 + l15 * 32 + ((g ^ rsw) * 8)];
      int ac = ((kk * 4 + g) ^ swz) * 8;
      bf16x8 a0 = *(const bf16x8*)&As[(l15) * 256 + ac];
      bf16x8 a1 = *(const bf16x8*)&As[(16 + l15) * 256 + ac];
      bf16x8 a2 = *(const bf16x8*)&As[(32 + l15) * 256 + ac];
      bf16x8 a3 = *(const bf16x8*)&As[(48 + l15) * 256 + ac];
      asm volatile("s_waitcnt lgkmcnt(0)" ::: "memory"); // slot reads done -> reusable
      if (kk < 4) {          // refill with S1 slice kk+4 (same ec)
        gl_lds16(W1t + (size_t)(ew + lr) * 256 + (kk + 4) * 32 + lc,
                 &WR[wb + slot * 1024]);
        gl_lds16(W2t + (size_t)(ew + lr) * 256 + (kk + 4) * 32 + lc,
                 &WR[wb + slot * 1024 + 512]);
      } else {               // refill with W3 slice: k2=(kk-4)>>1, nh=kk&1
        int k2i = (kk - 4) >> 1, nh = kk & 1;
        const short* g3 = W3t + (size_t)(w * 64 + nh * 32 + lr) * 1024
                          + e0 + k2i * 32 + lc;
        gl_lds16(g3, &WR[wb + slot * 1024]);
        gl_lds16(g3 + 16 * 1024, &WR[wb + slot * 1024 + 512]);
      }
      h1[0] = mfma16(w1f, a0, h1[0]); h2[0] = mfma16(w2f, a0, h2[0]);
      h1[1] = mfma16(w1f, a1, h1[1]); h2[1] = mfma16(w2f, a1, h2[1]);
      h1[2] = mfma16(w1f, a2, h1[2]); h2[2] = mfma16(w2f, a2, h2[2]);
      h1[3] = mfma16(w1f, a3, h1[3]); h2[3] = mfma16(w2f, a3, h2[3]);
    }
    // ---- silu(h1)*h2 -> Hs (lane holds 4 consecutive e for col m) ----
    #pragma unroll
    for (int tm = 0; tm < 4; ++tm) {
      int m = tm * 16 + l15;
      float a0 = h1[tm][0], a1 = h1[tm][1], a2 = h1[tm][2], a3 = h1[tm][3];
      float v0 = a0 * h2[tm][0] * sigf(a0);
      float v1 = a1 * h2[tm][1] * sigf(a1);
      float v2 = a2 * h2[tm][2] * sigf(a2);
      float v3 = a3 * h2[tm][3] * sigf(a3);
      uint2 pk;
      pk.x = cvtpk(v0, v1);
      pk.y = cvtpk(v2, v3);
      *(uint2*)&Hs[m * 72 + w16 + g * 4] = pk;
    }
    // ---- barrier 1: Hs writes visible (lgkm-only; DMA stays in flight) ----
    asm volatile("s_waitcnt lgkmcnt(0)" ::: "memory");
    __builtin_amdgcn_sched_barrier(0);
    __builtin_amdgcn_s_barrier();
    __builtin_amdgcn_sched_barrier(0);
    // ---- stage2: 2 e-half phases ----
    #pragma unroll
    for (int k2 = 0; k2 < 2; ++k2) {
      asm volatile("s_waitcnt vmcnt(4)" ::: "memory");   // W3 halves resident
      bf16x8 hf[4];
      #pragma unroll
      for (int tm = 0; tm < 4; ++tm)
        hf[tm] = *(const bf16x8*)&Hs[(tm * 16 + l15) * 72 + k2 * 32 + g * 8];
      bf16x8 w3f[4];
      #pragma unroll
      for (int tn = 0; tn < 4; ++tn)
        w3f[tn] = *(const bf16x8*)&WR[wb + (k2 * 2 + (tn >> 1)) * 1024
                                     + (tn & 1) * 512 + l15 * 32 + ((g ^ rsw) * 8)];
      asm volatile("s_waitcnt lgkmcnt(0)" ::: "memory"); // slots reusable
      // prefetch next-ec S1 slices (k2*2), (k2*2+1) into the freed slots
      gl_lds16(W1t + (size_t)(e0n + w16 + lr) * 256 + (k2 * 2) * 32 + lc,
               &WR[wb + (k2 * 2) * 1024]);
      gl_lds16(W2t + (size_t)(e0n + w16 + lr) * 256 + (k2 * 2) * 32 + lc,
               &WR[wb + (k2 * 2) * 1024 + 512]);
      gl_lds16(W1t + (size_t)(e0n + w16 + lr) * 256 + (k2 * 2 + 1) * 32 + lc,
               &WR[wb + (k2 * 2 + 1) * 1024]);
      gl_lds16(W2t + (size_t)(e0n + w16 + lr) * 256 + (k2 * 2 + 1) * 32 + lc,
               &WR[wb + (k2 * 2 + 1) * 1024 + 512]);
      #pragma unroll
      for (int tn = 0; tn < 4; ++tn)
        #pragma unroll
        for (int tm = 0; tm < 4; ++tm)
          oacc[tm][tn] = mfma16(hf[tm], w3f[tn], oacc[tm][tn]);
    }
    // ---- barrier 2: Hs reads done before next chunk overwrites ----
    __builtin_amdgcn_sched_barrier(0);
    __builtin_amdgcn_s_barrier();
    __builtin_amdgcn_sched_barrier(0);
  }
  // ---- FINAL DRAIN: no LDS-DMA may be outstanding at s_endpgm ----
  asm volatile("s_waitcnt vmcnt(0)" ::: "memory");
  // ---- final out write (nt) ----
  float sa = sigf(alpha[0]);
  #pragma unroll
  for (int tn = 0; tn < 4; ++tn) {
    int n = w * 64 + tn * 16 + l15;
    #pragma unroll
    for (int tm = 0; tm < 4; ++tm)
      #pragma unroll
      for (int r = 0; r < 4; ++r) {
        int m = row0 + tm * 16 + g * 4 + r;
        __builtin_nontemporal_store(sa * oacc[tm][tn][r], &out[(size_t)m * 256 + n]);
      }
  }
}

// ---------------------------------------------------------------------------
// K5: attention pass 1. One block per (b,t,h). Row softmax P1 over r,
// v1[r][d] = sum_n P1[n][r]*xv[n][d], plus online column (over n) max/sum.
// All xr traffic is within one half-wave (writer and reader share nl), and
// same-wave DS ops are processed in order -> NO in-loop barriers needed.
// Softmax division -> v_rcp_f32 (denominator >= 1, tolerance 7.8e-3 >> 1ulp).
// ---------------------------------------------------------------------------
__global__ __launch_bounds__(256) void k_attn1(
    const short* __restrict__ attnb, const short* __restrict__ xvb,
    float* __restrict__ v1buf, float* __restrict__ colmax, float* __restrict__ colsum)
{
  __shared__ float xr[8][32];
  __shared__ float red[8][32][32];
  __shared__ float mred[8][32], sred[8][32];
  int gid = blockIdx.x;            // bt*8 + h
  int bt = gid >> 3, h = gid & 7;
  int tid = threadIdx.x, r = tid & 31, nl = tid >> 5;
  int base = bt * NSEQ;
  float accd[32];
  #pragma unroll
  for (int d = 0; d < 32; ++d) accd[d] = 0.f;
  float mrun = -1e30f, srun = 0.f;
  for (int it = 0; it < 125; ++it) {
    int tok = base + it * 8 + nl;
    float a = b2f(attnb[(size_t)tok * 256 + h * 32 + r]);
    float rmax = a;
    #pragma unroll
    for (int mm = 16; mm > 0; mm >>= 1) rmax = fmaxf(rmax, __shfl_xor(rmax, mm));
    float ea = __expf(a - rmax);
    float rsum = ea;
    #pragma unroll
    for (int mm = 16; mm > 0; mm >>= 1) rsum += __shfl_xor(rsum, mm);
    float p1 = ea * frcp(rsum);
    float nm = fmaxf(mrun, a);                       // online col stats
    srun = srun * __expf(mrun - nm) + __expf(a - nm);
    mrun = nm;
    xr[nl][r] = b2f(xvb[(size_t)tok * 256 + h * 32 + r]);
    // same half-wave write->read: in-order DS pipeline, no barrier
    #pragma unroll
    for (int d = 0; d < 32; ++d) accd[d] += p1 * xr[nl][d];
  }
  #pragma unroll
  for (int d = 0; d < 32; ++d) red[nl][r][d] = accd[d];
  mred[nl][r] = mrun; sred[nl][r] = srun;
  __syncthreads();
  for (int s = 4; s > 0; s >>= 1) {
    if (nl < s)
      #pragma unroll
      for (int d = 0; d < 32; ++d) red[nl][r][d] += red[nl + s][r][d];
    __syncthreads();
  }
  if (nl == 0) {
    for (int d = 0; d < 32; ++d) v1buf[gid * 1024 + r * 32 + d] = red[0][r][d];
    float Mv = -1e30f;
    for (int j = 0; j < 8; ++j) Mv = fmaxf(Mv, mred[j][r]);
    float Sv = 0.f;
    for (int j = 0; j < 8; ++j) Sv += sred[j][r] * __expf(mred[j][r] - Mv);
    colmax[gid * 32 + r] = Mv;
    colsum[gid * 32 + r] = Sv;
  }
}

// ---------------------------------------------------------------------------
// K6: attention pass 2 + final blend.
// v2[n][d] = sum_r P2[n][r]*v1[r][d]. NEW: each thread's v1 column (32 f32)
// is loop-invariant -> hoisted to VGPRs (static indices); no v1s LDS staging,
// no barriers at all. p2s stays LDS (same-half-wave broadcast, in-order).
// ---------------------------------------------------------------------------
__global__ __launch_bounds__(256) void k_attn2(
    const short* __restrict__ attnb, const short* __restrict__ xvb,
    const float* __restrict__ v1buf, const float* __restrict__ colmax,
    const float* __restrict__ colsum, const float* __restrict__ mha_alpha,
    const float* __restrict__ mha_beta, const float* __restrict__ beta,
    float* __restrict__ out)
{
  __shared__ float p2s[256];
  int bt = blockIdx.x, chunk = blockIdx.y;
  int tid = threadIdx.x;
  int h = tid >> 5, d = tid & 31;
  float v1reg[32];
  #pragma unroll
  for (int rr = 0; rr < 32; ++rr)
    v1reg[rr] = v1buf[(size_t)bt * 8192 + h * 1024 + rr * 32 + d];
  float cm  = colmax[bt * 256 + tid];
  float rcs = 1.f / colsum[bt * 256 + tid];
  float sa = sigf(mha_alpha[h]), sb = sigf(mha_beta[h]);
  float sbeta = sigf(beta[0]);
  int tok0 = bt * NSEQ + chunk * 100;
  for (int tl = 0; tl < 100; ++tl) {
    int tok = tok0 + tl;
    float a = b2f(attnb[(size_t)tok * 256 + tid]);
    p2s[tid] = __expf(a - cm) * rcs;
    float xvv = b2f(xvb[(size_t)tok * 256 + tid]);
    // same half-wave write->read: in-order DS pipeline, no barrier
    float v2 = 0.f;
    #pragma unroll
    for (int rr = 0; rr < 32; ++rr)
      v2 += p2s[h * 32 + rr] * v1reg[rr];
    out[(size_t)tok * 256 + tid] += sbeta * (sa * xvv + sb * v2);
  }
}

// ---------------------------------------------------------------------------
extern "C" void kernel_launch(void* const* d_in, const int* in_sizes, int n_in,
                              void* d_out, int out_size, void* d_ws, size_t ws_size,
                              hipStream_t stream) {
  const float* x        = (const float*)d_in[0];
  const float* z        = (const float*)d_in[1];
  const float* norm1_w  = (const float*)d_in[2];
  const float* norm2_w  = (const float*)d_in[3];
  const float* alpha    = (const float*)d_in[4];
  const float* beta     = (const float*)d_in[5];
  const float* gamma    = (const float*)d_in[6];
  const float* delta    = (const float*)d_in[7];
  const float* Wq       = (const float*)d_in[8];
  const float* bq       = (const float*)d_in[9];
  const float* key      = (const float*)d_in[10];
  const float* Wv       = (const float*)d_in[11];
  const float* bv       = (const float*)d_in[12];
  const float* mha_a    = (const float*)d_in[13];
  const float* mha_b    = (const float*)d_in[14];
  const float* W1       = (const float*)d_in[15];
  const float* b1       = (const float*)d_in[16];
  const float* W2       = (const float*)d_in[17];
  const float* b2       = (const float*)d_in[18];
  const float* W3       = (const float*)d_in[19];
  const float* b3       = (const float*)d_in[20];
  float* out = (float*)d_out;
  char* ws = (char*)d_ws;

  short* x1b   = (short*)(ws);
  short* z1b   = (short*)(ws + 49152000);
  short* xvb   = (short*)(ws + 98304000);
  short* attnb = (short*)(ws + 147456000);
  short* W1t   = (short*)(ws + 196608000);
  short* W2t   = (short*)(ws + 197132288);
  short* W3t   = (short*)(ws + 197656576);
  short* Wvt   = (short*)(ws + 198180864);
  short* Wqkt  = (short*)(ws + 198311936);
  float* bqk   = (float*)(ws + 198443008);
  float* v1buf = (float*)(ws + 198444032);
  float* colmax= (float*)(ws + 201589760);
  float* colsum= (float*)(ws + 201688064);

  hipLaunchKernelGGL(k_prep, dim3(1024), dim3(256), 0, stream,
                     Wq, bq, key, Wv, W1, W2, W3, W1t, W2t, W3t, Wvt, Wqkt, bqk);
  hipLaunchKernelGGL(k_norm, dim3(MT / 4), dim3(256), 0, stream,
                     x, z, norm1_w, norm2_w, gamma, delta, x1b, z1b);
  hipLaunchKernelGGL(k_gemm_fullN, dim3(MT / 64), dim3(256), 0, stream,
                     z1b, Wqkt, bqk, attnb);
  hipLaunchKernelGGL(k_gemm_fullN, dim3(MT / 64), dim3(256), 0, stream,
                     x1b, Wvt, bv, xvb);
  hipLaunchKernelGGL(k_ffn, dim3(MT / 64), dim3(256), 0, stream,
                     x1b, W1t, W2t, W3t, b1, b2, b3, alpha, out);
  hipLaunchKernelGGL(k_attn1, dim3(NBT * 8), dim3(256), 0, stream,
                     attnb, xvb, v1buf, colmax, colsum);
  hipLaunchKernelGGL(k_attn2, dim3(NBT, 10), dim3(256), 0, stream,
                     attnb, xvb, v1buf, colmax, colsum, mha_a, mha_b, beta, out);
}

// Round 8
// 689.937 us; speedup vs baseline: 1.5234x; 1.0535x over previous
//
#include <hip/hip_runtime.h>
#include <math.h>

// Shapes (hardcoded from reference): B=8,T=12,N=1000,D=256,H=8,R=32,HD=32,E=1024
#define MT 96000   // B*T*N tokens
#define DD 256
#define EE 1024
#define NBT 96     // B*T
#define NSEQ 1000

typedef __attribute__((ext_vector_type(8))) short bf16x8;
typedef __attribute__((ext_vector_type(4))) short bf16x4;
typedef __attribute__((ext_vector_type(4))) float f32x4;

__device__ __forceinline__ short f2b(float f) {
  union { float f; unsigned u; } v; v.f = f;
  unsigned r = (v.u + 0x7FFFu + ((v.u >> 16) & 1u)) >> 16;
  return (short)r;
}
__device__ __forceinline__ float b2f(short s) {
  union { unsigned u; float f; } v; v.u = ((unsigned)(unsigned short)s) << 16;
  return v.f;
}
__device__ __forceinline__ float sigf(float x) { return 1.f / (1.f + __expf(-x)); }
__device__ __forceinline__ f32x4 mfma16(bf16x8 a, bf16x8 b, f32x4 c) {
  return __builtin_amdgcn_mfma_f32_16x16x32_bf16(a, b, c, 0, 0, 0);
}
// packed f32x2 -> bf16x2 (RNE), single VALU inst
__device__ __forceinline__ unsigned cvtpk(float lo, float hi) {
  unsigned r;
  asm("v_cvt_pk_bf16_f32 %0, %1, %2" : "=v"(r) : "v"(lo), "v"(hi));
  return r;
}
// fast f32 reciprocal (v_rcp_f32, ~1ulp) — safe for softmax denominators (>0)
__device__ __forceinline__ float frcp(float x) {
  float r;
  asm("v_rcp_f32 %0, %1" : "=v"(r) : "v"(x));
  return r;
}
// async global->LDS DMA: 64 lanes x 16B = 1KB per call; LDS dest is
// wave-uniform base + lane*16; global src is per-lane.
__device__ __forceinline__ void gl_lds16(const short* gp, short* lp) {
  __builtin_amdgcn_global_load_lds(
      (const __attribute__((address_space(1))) void*)gp,
      (__attribute__((address_space(3))) void*)lp, 16, 0, 0);
}

// ---------------------------------------------------------------------------
// K0: weight prep. Transposed bf16 weights ([out][in] so B-fragments are 16B
// contiguous k-octets), plus fused Wqk = (Wq . key)/sqrt(HD) and bqk.
// ---------------------------------------------------------------------------
__global__ __launch_bounds__(256) void k_prep(
    const float* __restrict__ Wq, const float* __restrict__ bq,
    const float* __restrict__ key, const float* __restrict__ Wv,
    const float* __restrict__ W1, const float* __restrict__ W2,
    const float* __restrict__ W3,
    short* __restrict__ W1t, short* __restrict__ W2t, short* __restrict__ W3t,
    short* __restrict__ Wvt, short* __restrict__ Wqkt, float* __restrict__ bqk)
{
  int i = blockIdx.x * 256 + threadIdx.x;   // 0 .. 262143
  { int e = i >> 8, c = i & 255;            // W1t/W2t: [e][c]
    W1t[i] = f2b(W1[c * EE + e]);
    W2t[i] = f2b(W2[c * EE + e]); }
  { int n = i >> 10, e = i & 1023;          // W3t: [n][e]
    W3t[i] = f2b(W3[e * DD + n]); }
  if (i < 65536) {
    int n = i >> 8, c = i & 255;
    Wvt[i] = f2b(Wv[c * DD + n]);           // Wvt: [n][c]
    int h = n >> 5, r = n & 31;
    float acc = 0.f;
    for (int d = 0; d < 32; ++d)
      acc += Wq[c * DD + h * 32 + d] * key[(r * 8 + h) * 32 + d];
    Wqkt[i] = f2b(acc * 0.17677669529663687f);  // 1/sqrt(32)
  }
  if (i < 256) {
    int h = i >> 5, r = i & 31;
    float acc = 0.f;
    for (int d = 0; d < 32; ++d)
      acc += bq[h * 32 + d] * key[(r * 8 + h) * 32 + d];
    bqk[i] = acc * 0.17677669529663687f;
  }
}

// ---------------------------------------------------------------------------
// K_FUSED: norm + qk-GEMM + v-GEMM + SwiGLU-FFN over one 64-token tile.
// Phases (256 threads, 4 waves, barrier between phases):
//  P0 norm: per wave 16 tokens; x1 -> As (ffn swizzled layout), z1 -> Zs
//     (stride 264). x1b/z1b global buffers eliminated. Bb (b1,b2 bf16) staged.
//  P1 qk-GEMM: attnb = z1 @ Wqk^T + bqk  (gemm_fullN body, A from Zs).
//  P2 v-GEMM:  xvb   = x1 @ Wv^T  + bv   (A from swizzled As).
//     oacc init with b3 after P2 (all bias vmem issued before the sync).
//  explicit vmcnt(0)+lgkmcnt(0) drain + sync (clean ring counting), then
//  P3 FFN: v5.1 verbatim (4-slot/2KB per-wave DMA ring, vmcnt(6)/(4) counted
//     waits, 2 lgkm-only barriers per ec, wrap prefetch, final vmcnt(0) drain).
// LDS: As 32768 + U(Zs 33792 | WR 32768 + Hs 9216) 41984 + Bb 4096 = 78848 B
// -> 2 blocks/CU, same as the verified v5.1 k_ffn.
// ---------------------------------------------------------------------------
__global__ __launch_bounds__(256, 2) void k_fused(
    const float* __restrict__ x, const float* __restrict__ z,
    const float* __restrict__ nw1, const float* __restrict__ nw2,
    const float* __restrict__ gamma, const float* __restrict__ delta,
    const short* __restrict__ Wqkt, const float* __restrict__ bqk,
    const short* __restrict__ Wvt, const float* __restrict__ bv,
    const short* __restrict__ W1t, const short* __restrict__ W2t,
    const short* __restrict__ W3t,
    const float* __restrict__ b1, const float* __restrict__ b2,
    const float* __restrict__ b3, const float* __restrict__ alpha,
    short* __restrict__ attnb, short* __restrict__ xvb,
    float* __restrict__ out)
{
  __shared__ __align__(16) short As[16384];   // x1 tile [64][256], granule-swizzled
  __shared__ __align__(16) short U[20992];    // Zs [64][264]  |  WR 4x4096 + Hs [64][72]
  __shared__ __align__(16) short Bb[2048];    // b1,b2 as bf16
  short* Zs = U;
  short* WR = U;
  short* Hs = U + 16384;

  int row0 = blockIdx.x * 64;
  int tid = threadIdx.x, lane = tid & 63, w = tid >> 6;
  int l15 = lane & 15, g = lane >> 4;
  int swz = l15 & 7;
  int w16 = w * 16;
  int wb = w * 4096;                   // ring base (shorts)
  int lr = lane >> 2;                  // DMA source row
  int lc = (((lane & 3) ^ ((lane >> 3) & 3)) * 8);  // pre-swizzled src octet
  int rsw = (l15 >> 1) & 3;            // ring read-side XOR key

  // ================= P0: fused RMSNorm into LDS =================
  {
    float sg = sigf(gamma[0]), sd = sigf(delta[0]);
    float4 wv = ((const float4*)nw1)[lane];
    float4 w2v = ((const float4*)nw2)[lane];
    for (int t = 0; t < 16; ++t) {
      int tl = w16 + t;
      size_t rbase = (size_t)(row0 + tl) * 256;
      float4 xv = ((const float4*)(x + rbase))[lane];
      float ss = xv.x*xv.x + xv.y*xv.y + xv.z*xv.z + xv.w*xv.w;
      #pragma unroll
      for (int mm = 1; mm < 64; mm <<= 1) ss += __shfl_xor(ss, mm);
      float inv = rsqrtf(ss * 0.00390625f + 1e-6f);
      float xa = xv.x * inv * wv.x, xb = xv.y * inv * wv.y,
            xc = xv.z * inv * wv.z, xd = xv.w * inv * wv.w;
      bf16x4 xo = { f2b(xa), f2b(xb), f2b(xc), f2b(xd) };
      // element j = lane*4+i -> As[tl*256 + ((j>>3 ^ (tl&7))*8) + (j&7)]
      *(bf16x4*)&As[tl * 256 + (((lane >> 1) ^ (tl & 7)) * 8) + (lane & 1) * 4] = xo;
      float4 zv = ((const float4*)(z + rbase))[lane];
      float t0 = sg*xa + sd*zv.x, t1 = sg*xb + sd*zv.y,
            t2 = sg*xc + sd*zv.z, t3 = sg*xd + sd*zv.w;
      float s2 = t0*t0 + t1*t1 + t2*t2 + t3*t3;
      #pragma unroll
      for (int mm = 1; mm < 64; mm <<= 1) s2 += __shfl_xor(s2, mm);
      float inv2 = rsqrtf(s2 * 0.00390625f + 1e-6f);
      bf16x4 zo = { f2b(t0*inv2*w2v.x), f2b(t1*inv2*w2v.y),
                    f2b(t2*inv2*w2v.z), f2b(t3*inv2*w2v.w) };
      *(bf16x4*)&Zs[tl * 264 + lane * 4] = zo;
    }
    // stage b1/b2 as bf16 (vmem issued before first sync)
    float4 v1 = ((const float4*)b1)[tid];
    float4 v2 = ((const float4*)b2)[tid];
    bf16x4 p1 = { f2b(v1.x), f2b(v1.y), f2b(v1.z), f2b(v1.w) };
    bf16x4 p2 = { f2b(v2.x), f2b(v2.y), f2b(v2.z), f2b(v2.w) };
    *(bf16x4*)&Bb[tid * 4] = p1;
    *(bf16x4*)&Bb[1024 + tid * 4] = p2;
  }
  __syncthreads();

  // ================= P1: qk-GEMM (A = Zs) =================
  {
    f32x4 acc[4][4];
    #pragma unroll
    for (int tn = 0; tn < 4; ++tn) {
      float bb = bqk[w * 64 + tn * 16 + l15];
      #pragma unroll
      for (int tm = 0; tm < 4; ++tm) acc[tm][tn] = (f32x4){bb, bb, bb, bb};
    }
    #pragma unroll
    for (int kk = 0; kk < 8; ++kk) {
      bf16x8 af[4], wf[4];
      #pragma unroll
      for (int tm = 0; tm < 4; ++tm)
        af[tm] = *(const bf16x8*)&Zs[(tm * 16 + l15) * 264 + kk * 32 + g * 8];
      #pragma unroll
      for (int tn = 0; tn < 4; ++tn)
        wf[tn] = *(const bf16x8*)&Wqkt[(size_t)(w * 64 + tn * 16 + l15) * 256 + kk * 32 + g * 8];
      #pragma unroll
      for (int tn = 0; tn < 4; ++tn)
        #pragma unroll
        for (int tm = 0; tm < 4; ++tm)
          acc[tm][tn] = mfma16(af[tm], wf[tn], acc[tm][tn]);
    }
    #pragma unroll
    for (int tn = 0; tn < 4; ++tn) {
      int n = w * 64 + tn * 16 + l15;
      #pragma unroll
      for (int tm = 0; tm < 4; ++tm)
        #pragma unroll
        for (int r = 0; r < 4; ++r) {
          int m = row0 + tm * 16 + g * 4 + r;
          attnb[(size_t)m * 256 + n] = f2b(acc[tm][tn][r]);
        }
    }
  }
  // ================= P2: v-GEMM (A = swizzled As) =================
  {
    f32x4 acc[4][4];
    #pragma unroll
    for (int tn = 0; tn < 4; ++tn) {
      float bb = bv[w * 64 + tn * 16 + l15];
      #pragma unroll
      for (int tm = 0; tm < 4; ++tm) acc[tm][tn] = (f32x4){bb, bb, bb, bb};
    }
    #pragma unroll
    for (int kk = 0; kk < 8; ++kk) {
      bf16x8 af[4], wf[4];
      int ac = ((kk * 4 + g) ^ swz) * 8;
      #pragma unroll
      for (int tm = 0; tm < 4; ++tm)
        af[tm] = *(const bf16x8*)&As[(tm * 16 + l15) * 256 + ac];
      #pragma unroll
      for (int tn = 0; tn < 4; ++tn)
        wf[tn] = *(const bf16x8*)&Wvt[(size_t)(w * 64 + tn * 16 + l15) * 256 + kk * 32 + g * 8];
      #pragma unroll
      for (int tn = 0; tn < 4; ++tn)
        #pragma unroll
        for (int tm = 0; tm < 4; ++tm)
          acc[tm][tn] = mfma16(af[tm], wf[tn], acc[tm][tn]);
    }
    #pragma unroll
    for (int tn = 0; tn < 4; ++tn) {
      int n = w * 64 + tn * 16 + l15;
      #pragma unroll
      for (int tm = 0; tm < 4; ++tm)
        #pragma unroll
        for (int r = 0; r < 4; ++r) {
          int m = row0 + tm * 16 + g * 4 + r;
          xvb[(size_t)m * 256 + n] = f2b(acc[tm][tn][r]);
        }
    }
  }
  // ---- oacc init with b3 (vmem before the drain-sync) ----
  f32x4 oacc[4][4];
  #pragma unroll
  for (int tn = 0; tn < 4; ++tn) {
    float bb = b3[w * 64 + tn * 16 + l15];
    #pragma unroll
    for (int tm = 0; tm < 4; ++tm) oacc[tm][tn] = (f32x4){bb, bb, bb, bb};
  }
  // ---- explicit full drain (hardening: ring-count base independent of
  //      compiler's __syncthreads lowering), then phase barrier ----
  __builtin_amdgcn_sched_barrier(0);
  asm volatile("s_waitcnt vmcnt(0) lgkmcnt(0)" ::: "memory");
  __builtin_amdgcn_sched_barrier(0);
  __syncthreads();   // Zs now dead; WR/Hs take over the U region

  // ================= P3: FFN (v5.1 verbatim) =================
  // prologue: issue ec0 S1 slices kk=0..3 into slots 0..3
  #pragma unroll
  for (int s = 0; s < 4; ++s) {
    gl_lds16(W1t + (size_t)(w16 + lr) * 256 + s * 32 + lc, &WR[wb + s * 1024]);
    gl_lds16(W2t + (size_t)(w16 + lr) * 256 + s * 32 + lc, &WR[wb + s * 1024 + 512]);
  }

  for (int ec = 0; ec < 16; ++ec) {
    int e0 = ec * 64;
    int e0n = ((ec + 1) & 15) * 64;    // wrap keeps vmcnt accounting uniform
    int ew = e0 + w16;
    // h accumulators init from Bb (C rows = e = ew + g*4 + r)
    bf16x4 c1b = *(const bf16x4*)&Bb[ew + g * 4];
    bf16x4 c2b = *(const bf16x4*)&Bb[1024 + ew + g * 4];
    f32x4 i1 = { b2f(c1b[0]), b2f(c1b[1]), b2f(c1b[2]), b2f(c1b[3]) };
    f32x4 i2 = { b2f(c2b[0]), b2f(c2b[1]), b2f(c2b[2]), b2f(c2b[3]) };
    f32x4 h1[4], h2[4];
    #pragma unroll
    for (int tm = 0; tm < 4; ++tm) { h1[tm] = i1; h2[tm] = i2; }
    // ---- stage1: 8 k-phases; slice kk from slot kk&3, then refill slot ----
    #pragma unroll
    for (int kk = 0; kk < 8; ++kk) {
      int slot = kk & 3;
      asm volatile("s_waitcnt vmcnt(6)" ::: "memory");   // slice kk resident
      bf16x8 w1f = *(const bf16x8*)&WR[wb + slot * 1024 + l15 * 32 + ((g ^ rsw) * 8)];
      bf16x8 w2f = *(const bf16x8*)&WR[wb + slot * 1024 + 512 + l15 * 32 + ((g ^ rsw) * 8)];
      int ac = ((kk * 4 + g) ^ swz) * 8;
      bf16x8 a0 = *(const bf16x8*)&As[(l15) * 256 + ac];
      bf16x8 a1 = *(const bf16x8*)&As[(16 + l15) * 256 + ac];
      bf16x8 a2 = *(const bf16x8*)&As[(32 + l15) * 256 + ac];
      bf16x8 a3 = *(const bf16x8*)&As[(48 + l15) * 256 + ac];
      asm volatile("s_waitcnt lgkmcnt(0)" ::: "memory"); // slot reads done -> reusable
      if (kk < 4) {          // refill with S1 slice kk+4 (same ec)
        gl_lds16(W1t + (size_t)(ew + lr) * 256 + (kk + 4) * 32 + lc,
                 &WR[wb + slot * 1024]);
        gl_lds16(W2t + (size_t)(ew + lr) * 256 + (kk + 4) * 32 + lc,
                 &WR[wb + slot * 1024 + 512]);
      } else {               // refill with W3 slice: k2=(kk-4)>>1, nh=kk&1
        int k2i = (kk - 4) >> 1, nh = kk & 1;
        const short* g3 = W3t + (size_t)(w * 64 + nh * 32 + lr) * 1024
                          + e0 + k2i * 32 + lc;
        gl_lds16(g3, &WR[wb + slot * 1024]);
        gl_lds16(g3 + 16 * 1024, &WR[wb + slot * 1024 + 512]);
      }
      h1[0] = mfma16(w1f, a0, h1[0]); h2[0] = mfma16(w2f, a0, h2[0]);
      h1[1] = mfma16(w1f, a1, h1[1]); h2[1] = mfma16(w2f, a1, h2[1]);
      h1[2] = mfma16(w1f, a2, h1[2]); h2[2] = mfma16(w2f, a2, h2[2]);
      h1[3] = mfma16(w1f, a3, h1[3]); h2[3] = mfma16(w2f, a3, h2[3]);
    }
    // ---- silu(h1)*h2 -> Hs (lane holds 4 consecutive e for col m) ----
    #pragma unroll
    for (int tm = 0; tm < 4; ++tm) {
      int m = tm * 16 + l15;
      float a0 = h1[tm][0], a1 = h1[tm][1], a2 = h1[tm][2], a3 = h1[tm][3];
      float v0 = a0 * h2[tm][0] * sigf(a0);
      float v1 = a1 * h2[tm][1] * sigf(a1);
      float v2 = a2 * h2[tm][2] * sigf(a2);
      float v3 = a3 * h2[tm][3] * sigf(a3);
      uint2 pk;
      pk.x = cvtpk(v0, v1);
      pk.y = cvtpk(v2, v3);
      *(uint2*)&Hs[m * 72 + w16 + g * 4] = pk;
    }
    // ---- barrier 1: Hs writes visible (lgkm-only; DMA stays in flight) ----
    asm volatile("s_waitcnt lgkmcnt(0)" ::: "memory");
    __builtin_amdgcn_sched_barrier(0);
    __builtin_amdgcn_s_barrier();
    __builtin_amdgcn_sched_barrier(0);
    // ---- stage2: 2 e-half phases ----
    #pragma unroll
    for (int k2 = 0; k2 < 2; ++k2) {
      asm volatile("s_waitcnt vmcnt(4)" ::: "memory");   // W3 halves resident
      bf16x8 hf[4];
      #pragma unroll
      for (int tm = 0; tm < 4; ++tm)
        hf[tm] = *(const bf16x8*)&Hs[(tm * 16 + l15) * 72 + k2 * 32 + g * 8];
      bf16x8 w3f[4];
      #pragma unroll
      for (int tn = 0; tn < 4; ++tn)
        w3f[tn] = *(const bf16x8*)&WR[wb + (k2 * 2 + (tn >> 1)) * 1024
                                     + (tn & 1) * 512 + l15 * 32 + ((g ^ rsw) * 8)];
      asm volatile("s_waitcnt lgkmcnt(0)" ::: "memory"); // slots reusable
      // prefetch next-ec S1 slices (k2*2), (k2*2+1) into the freed slots
      gl_lds16(W1t + (size_t)(e0n + w16 + lr) * 256 + (k2 * 2) * 32 + lc,
               &WR[wb + (k2 * 2) * 1024]);
      gl_lds16(W2t + (size_t)(e0n + w16 + lr) * 256 + (k2 * 2) * 32 + lc,
               &WR[wb + (k2 * 2) * 1024 + 512]);
      gl_lds16(W1t + (size_t)(e0n + w16 + lr) * 256 + (k2 * 2 + 1) * 32 + lc,
               &WR[wb + (k2 * 2 + 1) * 1024]);
      gl_lds16(W2t + (size_t)(e0n + w16 + lr) * 256 + (k2 * 2 + 1) * 32 + lc,
               &WR[wb + (k2 * 2 + 1) * 1024 + 512]);
      #pragma unroll
      for (int tn = 0; tn < 4; ++tn)
        #pragma unroll
        for (int tm = 0; tm < 4; ++tm)
          oacc[tm][tn] = mfma16(hf[tm], w3f[tn], oacc[tm][tn]);
    }
    // ---- barrier 2: Hs reads done before next chunk overwrites ----
    __builtin_amdgcn_sched_barrier(0);
    __builtin_amdgcn_s_barrier();
    __builtin_amdgcn_sched_barrier(0);
  }
  // ---- FINAL DRAIN: no LDS-DMA may be outstanding at s_endpgm ----
  asm volatile("s_waitcnt vmcnt(0)" ::: "memory");
  // ---- final out write (nt) ----
  float sa = sigf(alpha[0]);
  #pragma unroll
  for (int tn = 0; tn < 4; ++tn) {
    int n = w * 64 + tn * 16 + l15;
    #pragma unroll
    for (int tm = 0; tm < 4; ++tm)
      #pragma unroll
      for (int r = 0; r < 4; ++r) {
        int m = row0 + tm * 16 + g * 4 + r;
        __builtin_nontemporal_store(sa * oacc[tm][tn][r], &out[(size_t)m * 256 + n]);
      }
  }
}

// ---------------------------------------------------------------------------
// K5: attention pass 1 (unchanged from r6, passed). One block per (b,t,h).
// ---------------------------------------------------------------------------
__global__ __launch_bounds__(256) void k_attn1(
    const short* __restrict__ attnb, const short* __restrict__ xvb,
    float* __restrict__ v1buf, float* __restrict__ colmax, float* __restrict__ colsum)
{
  __shared__ float xr[8][32];
  __shared__ float red[8][32][32];
  __shared__ float mred[8][32], sred[8][32];
  int gid = blockIdx.x;            // bt*8 + h
  int bt = gid >> 3, h = gid & 7;
  int tid = threadIdx.x, r = tid & 31, nl = tid >> 5;
  int base = bt * NSEQ;
  float accd[32];
  #pragma unroll
  for (int d = 0; d < 32; ++d) accd[d] = 0.f;
  float mrun = -1e30f, srun = 0.f;
  for (int it = 0; it < 125; ++it) {
    int tok = base + it * 8 + nl;
    float a = b2f(attnb[(size_t)tok * 256 + h * 32 + r]);
    float rmax = a;
    #pragma unroll
    for (int mm = 16; mm > 0; mm >>= 1) rmax = fmaxf(rmax, __shfl_xor(rmax, mm));
    float ea = __expf(a - rmax);
    float rsum = ea;
    #pragma unroll
    for (int mm = 16; mm > 0; mm >>= 1) rsum += __shfl_xor(rsum, mm);
    float p1 = ea * frcp(rsum);
    float nm = fmaxf(mrun, a);                       // online col stats
    srun = srun * __expf(mrun - nm) + __expf(a - nm);
    mrun = nm;
    xr[nl][r] = b2f(xvb[(size_t)tok * 256 + h * 32 + r]);
    // same half-wave write->read: in-order DS pipeline, no barrier
    #pragma unroll
    for (int d = 0; d < 32; ++d) accd[d] += p1 * xr[nl][d];
  }
  #pragma unroll
  for (int d = 0; d < 32; ++d) red[nl][r][d] = accd[d];
  mred[nl][r] = mrun; sred[nl][r] = srun;
  __syncthreads();
  for (int s = 4; s > 0; s >>= 1) {
    if (nl < s)
      #pragma unroll
      for (int d = 0; d < 32; ++d) red[nl][r][d] += red[nl + s][r][d];
    __syncthreads();
  }
  if (nl == 0) {
    for (int d = 0; d < 32; ++d) v1buf[gid * 1024 + r * 32 + d] = red[0][r][d];
    float Mv = -1e30f;
    for (int j = 0; j < 8; ++j) Mv = fmaxf(Mv, mred[j][r]);
    float Sv = 0.f;
    for (int j = 0; j < 8; ++j) Sv += sred[j][r] * __expf(mred[j][r] - Mv);
    colmax[gid * 32 + r] = Mv;
    colsum[gid * 32 + r] = Sv;
  }
}

// ---------------------------------------------------------------------------
// K6: attention pass 2 + final blend (unchanged from r6, passed).
// ---------------------------------------------------------------------------
__global__ __launch_bounds__(256) void k_attn2(
    const short* __restrict__ attnb, const short* __restrict__ xvb,
    const float* __restrict__ v1buf, const float* __restrict__ colmax,
    const float* __restrict__ colsum, const float* __restrict__ mha_alpha,
    const float* __restrict__ mha_beta, const float* __restrict__ beta,
    float* __restrict__ out)
{
  __shared__ float p2s[256];
  int bt = blockIdx.x, chunk = blockIdx.y;
  int tid = threadIdx.x;
  int h = tid >> 5, d = tid & 31;
  float v1reg[32];
  #pragma unroll
  for (int rr = 0; rr < 32; ++rr)
    v1reg[rr] = v1buf[(size_t)bt * 8192 + h * 1024 + rr * 32 + d];
  float cm  = colmax[bt * 256 + tid];
  float rcs = 1.f / colsum[bt * 256 + tid];
  float sa = sigf(mha_alpha[h]), sb = sigf(mha_beta[h]);
  float sbeta = sigf(beta[0]);
  int tok0 = bt * NSEQ + chunk * 100;
  for (int tl = 0; tl < 100; ++tl) {
    int tok = tok0 + tl;
    float a = b2f(attnb[(size_t)tok * 256 + tid]);
    p2s[tid] = __expf(a - cm) * rcs;
    float xvv = b2f(xvb[(size_t)tok * 256 + tid]);
    // same half-wave write->read: in-order DS pipeline, no barrier
    float v2 = 0.f;
    #pragma unroll
    for (int rr = 0; rr < 32; ++rr)
      v2 += p2s[h * 32 + rr] * v1reg[rr];
    out[(size_t)tok * 256 + tid] += sbeta * (sa * xvv + sb * v2);
  }
}

// ---------------------------------------------------------------------------
extern "C" void kernel_launch(void* const* d_in, const int* in_sizes, int n_in,
                              void* d_out, int out_size, void* d_ws, size_t ws_size,
                              hipStream_t stream) {
  const float* x        = (const float*)d_in[0];
  const float* z        = (const float*)d_in[1];
  const float* norm1_w  = (const float*)d_in[2];
  const float* norm2_w  = (const float*)d_in[3];
  const float* alpha    = (const float*)d_in[4];
  const float* beta     = (const float*)d_in[5];
  const float* gamma    = (const float*)d_in[6];
  const float* delta    = (const float*)d_in[7];
  const float* Wq       = (const float*)d_in[8];
  const float* bq       = (const float*)d_in[9];
  const float* key      = (const float*)d_in[10];
  const float* Wv       = (const float*)d_in[11];
  const float* bv       = (const float*)d_in[12];
  const float* mha_a    = (const float*)d_in[13];
  const float* mha_b    = (const float*)d_in[14];
  const float* W1       = (const float*)d_in[15];
  const float* b1       = (const float*)d_in[16];
  const float* W2       = (const float*)d_in[17];
  const float* b2       = (const float*)d_in[18];
  const float* W3       = (const float*)d_in[19];
  const float* b3       = (const float*)d_in[20];
  float* out = (float*)d_out;
  char* ws = (char*)d_ws;

  short* xvb   = (short*)(ws + 98304000);
  short* attnb = (short*)(ws + 147456000);
  short* W1t   = (short*)(ws + 196608000);
  short* W2t   = (short*)(ws + 197132288);
  short* W3t   = (short*)(ws + 197656576);
  short* Wvt   = (short*)(ws + 198180864);
  short* Wqkt  = (short*)(ws + 198311936);
  float* bqk   = (float*)(ws + 198443008);
  float* v1buf = (float*)(ws + 198444032);
  float* colmax= (float*)(ws + 201589760);
  float* colsum= (float*)(ws + 201688064);

  hipLaunchKernelGGL(k_prep, dim3(1024), dim3(256), 0, stream,
                     Wq, bq, key, Wv, W1, W2, W3, W1t, W2t, W3t, Wvt, Wqkt, bqk);
  hipLaunchKernelGGL(k_fused, dim3(MT / 64), dim3(256), 0, stream,
                     x, z, norm1_w, norm2_w, gamma, delta,
                     Wqkt, bqk, Wvt, bv, W1t, W2t, W3t,
                     b1, b2, b3, alpha, attnb, xvb, out);
  hipLaunchKernelGGL(k_attn1, dim3(NBT * 8), dim3(256), 0, stream,
                     attnb, xvb, v1buf, colmax, colsum);
  hipLaunchKernelGGL(k_attn2, dim3(NBT, 10), dim3(256), 0, stream,
                     attnb, xvb, v1buf, colmax, colsum, mha_a, mha_b, beta, out);
}